// Round 7
// baseline (227.405 us; speedup 1.0000x reference)
//
#include <hip/hip_runtime.h>
#include <hip/hip_bf16.h>
#include <stdint.h>

#define DEV __device__ __forceinline__

typedef __attribute__((ext_vector_type(8))) __bf16 bf16x8;
typedef __attribute__((ext_vector_type(4))) float f32x4;
typedef __attribute__((ext_vector_type(16))) float f32x16;
typedef __attribute__((ext_vector_type(4))) unsigned int u32x4;

#define LOG2E 1.44269504088896f

DEV unsigned short f2bf(float f) {
    union { float f; unsigned int u; } v; v.f = f;
    unsigned int u = v.u;
    return (unsigned short)((u + 0x7FFFu + ((u >> 16) & 1u)) >> 16);
}
DEV float bf2f(unsigned short s) {
    union { unsigned int u; float f; } v; v.u = ((unsigned int)s) << 16;
    return v.f;
}

DEV f32x4 mfma16(bf16x8 a, bf16x8 b, f32x4 c) {
    return __builtin_amdgcn_mfma_f32_16x16x32_bf16(a, b, c, 0, 0, 0);
}
DEV f32x16 mfma32(bf16x8 a, bf16x8 b, f32x16 c) {
    return __builtin_amdgcn_mfma_f32_32x32x16_bf16(a, b, c, 0, 0, 0);
}
DEV float exp2a(float x) { float r; asm("v_exp_f32 %0, %1" : "=v"(r) : "v"(x)); return r; }
DEV unsigned cvtpk(float lo, float hi) {
    unsigned r; asm("v_cvt_pk_bf16_f32 %0, %1, %2" : "=v"(r) : "v"(lo), "v"(hi)); return r;
}
// After call: x' = [x_lo | y_lo], y' = [x_hi | y_hi]   (lane blocks of 32) — verified R5
DEV void plswap(unsigned& x, unsigned& y) {
    asm volatile("v_permlane32_swap_b32 %0, %1" : "+v"(x), "+v"(y));
}

#define GLOAD_LDS16(g, l)                                                          \
    __builtin_amdgcn_global_load_lds((__attribute__((address_space(1))) void*)(g), \
                                     (__attribute__((address_space(3))) void*)(l), \
                                     16, 0, 0)

// ---------------- merged f32 -> bf16 converts (7 slices in one launch) ----------------
__global__ void k_cvt_all(const float* __restrict__ i0, const float* __restrict__ i1,
                          const float* __restrict__ i2, const float* __restrict__ i3,
                          const float* __restrict__ i4, const float* __restrict__ i5,
                          const float* __restrict__ i6,
                          unsigned short* __restrict__ o0, unsigned short* __restrict__ o1,
                          unsigned short* __restrict__ o2, unsigned short* __restrict__ o3,
                          unsigned short* __restrict__ o4, unsigned short* __restrict__ o5,
                          unsigned short* __restrict__ o6) {
    int z = blockIdx.y;
    const float* in;
    unsigned short* out;
    int n; float scale = 1.0f;
    switch (z) {
        case 0: in = i0; out = o0; n = 8388608; break;
        case 1: in = i1; out = o1; n = 8388608; break;
        case 2: in = i2; out = o2; n = 8388608; break;
        case 3: in = i3; out = o3; n = 1048576; scale = LOG2E; break;  // Wq: fold log2e
        case 4: in = i4; out = o4; n = 1048576; break;
        case 5: in = i5; out = o5; n = 1048576; break;
        default: in = i6; out = o6; n = 1048576; break;
    }
    int stride = gridDim.x * blockDim.x;
    for (int i = blockIdx.x * blockDim.x + threadIdx.x; i * 4 < n; i += stride) {
        float4 f = reinterpret_cast<const float4*>(in)[i];
        ushort4 o;
        o.x = f2bf(f.x * scale); o.y = f2bf(f.y * scale);
        o.z = f2bf(f.z * scale); o.w = f2bf(f.w * scale);
        reinterpret_cast<ushort4*>(out)[i] = o;
    }
}

// ---------------- fused QKV projection GEMM (1-D grid, XCD-owned A-panel rows) ----------
// decode: xcd=flat&7, bn=(flat>>3)&7, row=xcd*24+(flat>>6); z=row>>6, bm=row&63.
// Each XCD processes its 24 (z,bm) rows with all 8 bn consecutively -> A-panel (256KB)
// + weight (2MB) stay in that XCD's private L2.
// z=0: Qb (B*H,L,64), bias*log2e; z=1: Kb + biask (shfl-reduced); z=2: Vb natural.
__global__ __launch_bounds__(256) void k_gemm_qkv(
    const unsigned short* __restrict__ xq, const unsigned short* __restrict__ xk,
    const unsigned short* __restrict__ xv, const unsigned short* __restrict__ wq,
    const unsigned short* __restrict__ wk, const unsigned short* __restrict__ wv,
    const float* __restrict__ bq, const float* __restrict__ bk, const float* __restrict__ bv,
    unsigned short* __restrict__ Qb, unsigned short* __restrict__ Kb,
    unsigned short* __restrict__ Vb, float* __restrict__ biask) {
    __shared__ __align__(16) unsigned short As[128 * 64];
    __shared__ __align__(16) unsigned short Bs[128 * 64];
    const int flat = blockIdx.x;
    const int xcd = flat & 7;
    const int bn = (flat >> 3) & 7;
    const int row = xcd * 24 + (flat >> 6);
    const int z = row >> 6;
    const int bm = row & 63;

    const unsigned short* A  = z == 0 ? xq : (z == 1 ? xk : xv);
    const unsigned short* Bw = z == 0 ? wq : (z == 1 ? wk : wv);
    const float* bias = z == 0 ? bq : (z == 1 ? bk : bv);
    const float bscale = z == 0 ? LOG2E : 1.0f;
    const int K = 1024;

    const int tid = threadIdx.x;
    const int lane = tid & 63, w = tid >> 6;
    const int g = lane >> 4, cc = lane & 15;
    const int wm = w >> 1, wn = w & 1;

    f32x4 acc[4][4] = {};
    const int srow = lane >> 3;
    const int scol = (lane & 7) * 8;

    for (int kt = 0; kt < K; kt += 64) {
#pragma unroll
        for (int p = 0; p < 4; ++p) {
            int c = w * 4 + p;
            int rr = c * 8 + srow;
            const unsigned short* gA = A + (size_t)(bm * 128 + rr) * K + kt + scol;
            GLOAD_LDS16(gA, &As[c * 512]);
            const unsigned short* gB = Bw + (size_t)(bn * 128 + rr) * K + kt + scol;
            GLOAD_LDS16(gB, &Bs[c * 512]);
        }
        __syncthreads();
#pragma unroll
        for (int kc = 0; kc < 2; ++kc) {
            bf16x8 af[4], bf[4];
#pragma unroll
            for (int i = 0; i < 4; ++i) {
                af[i] = *reinterpret_cast<const bf16x8*>(&As[(wm * 64 + i * 16 + cc) * 64 + kc * 32 + g * 8]);
                bf[i] = *reinterpret_cast<const bf16x8*>(&Bs[(wn * 64 + i * 16 + cc) * 64 + kc * 32 + g * 8]);
            }
#pragma unroll
            for (int mi = 0; mi < 4; ++mi)
#pragma unroll
                for (int nj = 0; nj < 4; ++nj)
                    acc[mi][nj] = mfma16(af[mi], bf[nj], acc[mi][nj]);
        }
        __syncthreads();
    }

    unsigned short* out = z == 0 ? Qb : (z == 1 ? Kb : Vb);
    float sq[4][4];
#pragma unroll
    for (int mi = 0; mi < 4; ++mi)
#pragma unroll
        for (int r = 0; r < 4; ++r) sq[mi][r] = 0.f;

#pragma unroll
    for (int mi = 0; mi < 4; ++mi) {
#pragma unroll
        for (int nj = 0; nj < 4; ++nj) {
            int n = bn * 128 + wn * 64 + nj * 16 + cc;
            float bvv = bias[n] * bscale;
            int h = n >> 6, d = n & 63;
#pragma unroll
            for (int r = 0; r < 4; ++r) {
                int m = bm * 128 + wm * 64 + mi * 16 + g * 4 + r;
                unsigned short us = f2bf(acc[mi][nj][r] + bvv);
                int b = m >> 11, l = m & 2047;
                out[(((size_t)b * 16 + h) * 2048 + l) * 64 + d] = us;
                if (z == 1) { float vr = bf2f(us); sq[mi][r] += vr * vr; }
            }
        }
    }
    if (z == 1) {
        const int h = bn * 2 + wn;
#pragma unroll
        for (int mi = 0; mi < 4; ++mi)
#pragma unroll
            for (int r = 0; r < 4; ++r) {
                float s = sq[mi][r];
                s += __shfl_xor(s, 1); s += __shfl_xor(s, 2);
                s += __shfl_xor(s, 4); s += __shfl_xor(s, 8);
                if (cc == 0) {
                    int m = bm * 128 + wm * 64 + mi * 16 + g * 4 + r;
                    biask[(((size_t)(m >> 11)) * 16 + h) * 2048 + (m & 2047)] =
                        -0.5f * LOG2E * s;
                }
            }
    }
}

// ---------------- V transpose: (BH, L, 64) -> (BH, 64, L) ----------------
__global__ __launch_bounds__(256) void k_vt(const unsigned short* __restrict__ Vb,
                                            unsigned short* __restrict__ VbT) {
    __shared__ __align__(16) unsigned short T[64 * 72];
    const int blk = blockIdx.x;
    const int bh = blk >> 5, lt = blk & 31;
    const int tid = threadIdx.x;
    const int rr = tid >> 3, seg = tid & 7;
#pragma unroll
    for (int p = 0; p < 2; ++p) {
        int row = p * 32 + rr;
        const unsigned short* src = Vb + ((size_t)bh * 2048 + lt * 64 + row) * 64 + seg * 8;
        *reinterpret_cast<u32x4*>(&T[row * 72 + seg * 8]) = *reinterpret_cast<const u32x4*>(src);
    }
    __syncthreads();
#pragma unroll
    for (int p = 0; p < 2; ++p) {
        int d = p * 32 + rr;
        union { u32x4 v; unsigned short s[8]; } o;
#pragma unroll
        for (int j = 0; j < 8; ++j) o.s[j] = T[(seg * 8 + j) * 72 + d];
        unsigned short* dst = VbT + ((size_t)bh * 64 + d) * 2048 + lt * 64 + seg * 8;
        *reinterpret_cast<u32x4*>(dst) = o.v;
    }
}

// ---------------- final GEMM: d_out = Ob * Wo^T + bo (f32 out), XCD-remapped ----------------
__global__ __launch_bounds__(256) void k_gemm_out(const unsigned short* __restrict__ A,
                                                  const unsigned short* __restrict__ Bw,
                                                  const float* __restrict__ bias,
                                                  float* __restrict__ out) {
    __shared__ __align__(16) unsigned short As[128 * 64];
    __shared__ __align__(16) unsigned short Bs[128 * 64];
    const int K = 1024, N = 1024;
    const int flat = blockIdx.x;
    const int xcd = flat & 7;
    const int bn = (flat >> 3) & 7;
    const int bm = xcd * 8 + (flat >> 6);

    const int tid = threadIdx.x;
    const int lane = tid & 63, w = tid >> 6;
    const int g = lane >> 4, cc = lane & 15;
    const int wm = w >> 1, wn = w & 1;

    f32x4 acc[4][4] = {};
    const int srow = lane >> 3;
    const int scol = (lane & 7) * 8;

    for (int kt = 0; kt < K; kt += 64) {
#pragma unroll
        for (int p = 0; p < 4; ++p) {
            int c = w * 4 + p;
            int rr = c * 8 + srow;
            const unsigned short* gA = A + (size_t)(bm * 128 + rr) * K + kt + scol;
            GLOAD_LDS16(gA, &As[c * 512]);
            const unsigned short* gB = Bw + (size_t)(bn * 128 + rr) * K + kt + scol;
            GLOAD_LDS16(gB, &Bs[c * 512]);
        }
        __syncthreads();
#pragma unroll
        for (int kc = 0; kc < 2; ++kc) {
            bf16x8 af[4], bf[4];
#pragma unroll
            for (int i = 0; i < 4; ++i) {
                af[i] = *reinterpret_cast<const bf16x8*>(&As[(wm * 64 + i * 16 + cc) * 64 + kc * 32 + g * 8]);
                bf[i] = *reinterpret_cast<const bf16x8*>(&Bs[(wn * 64 + i * 16 + cc) * 64 + kc * 32 + g * 8]);
            }
#pragma unroll
            for (int mi = 0; mi < 4; ++mi)
#pragma unroll
                for (int nj = 0; nj < 4; ++nj)
                    acc[mi][nj] = mfma16(af[mi], bf[nj], acc[mi][nj]);
        }
        __syncthreads();
    }

#pragma unroll
    for (int mi = 0; mi < 4; ++mi) {
#pragma unroll
        for (int nj = 0; nj < 4; ++nj) {
            int n = bn * 128 + wn * 64 + nj * 16 + cc;
            float bvv = bias[n];
#pragma unroll
            for (int r = 0; r < 4; ++r) {
                int m = bm * 128 + wm * 64 + mi * 16 + g * 4 + r;
                out[(size_t)m * N + n] = acc[mi][nj][r] + bvv;
            }
        }
    }
}

// ---------------- flash attention: RBF scores bounded => NO online max ----------------
// p = exp2((qk - 0.5||k||^2) log2e); the -0.5||q||^2 row-constant cancels in softmax.
// Q (BH,L,64) bf16 pre-scaled by log2e; K (BH,L,64); VT (BH,64,L); biask = -0.5*log2e*||k||^2.
__global__ __launch_bounds__(256, 2) void k_attn5(const unsigned short* __restrict__ Q,
                                                  const unsigned short* __restrict__ K,
                                                  const unsigned short* __restrict__ VT,
                                                  const float* __restrict__ biask,
                                                  unsigned short* __restrict__ Ob) {
    // ushort offsets: K0=0, K1=4096, V0=8192, V1=12288, B0=16384, B1=16512.
    // Epilogue reuses [0, 18432) as 256x72 staging.
    __shared__ __align__(16) unsigned short SM[18432];
    const int tid = threadIdx.x;
    const int lane = tid & 63, w = tid >> 6;
    const int l31 = lane & 31, hi = lane >> 5, l7 = lane & 7;
    const int flat = blockIdx.x;
    const int bh = (flat & 7) * 8 + ((flat >> 3) & 7);   // XCD-locality remap (bijective)
    const int qt = flat >> 6;                            // 0..7 (256 queries per block)
    const size_t kvbase = (size_t)bh * 2048 * 64;
    const int q0 = qt * 256 + w * 64;

    // Q fragments (B-operand), two 32-query sub-blocks per wave
    bf16x8 qf[2][4];
#pragma unroll
    for (int qb = 0; qb < 2; ++qb)
#pragma unroll
        for (int kc = 0; kc < 4; ++kc)
            qf[qb][kc] = *reinterpret_cast<const bf16x8*>(
                Q + kvbase + (size_t)(q0 + qb * 32 + l31) * 64 + kc * 16 + hi * 8);

    f32x16 ot[2][2] = {};
    float lrun[2] = {0.f, 0.f};
    const int srow = lane >> 3;

    auto stage = [&](int buf, int t) {
        const int kO = buf ? 4096 : 0;
        const int vO = buf ? 12288 : 8192;
#pragma unroll
        for (int i = 0; i < 2; ++i) {
            int r = w * 16 + i * 8 + srow;
            int cb = l7 ^ (r & 7);   // pre-swizzled source -> linear LDS == swizzled layout
            const unsigned short* gk = K + kvbase + (size_t)(t * 64 + r) * 64 + cb * 8;
            GLOAD_LDS16(gk, &SM[kO + (w * 16 + i * 8) * 64]);
            const unsigned short* gv = VT + kvbase + (size_t)r * 2048 + t * 64 + cb * 8;
            GLOAD_LDS16(gv, &SM[vO + (w * 16 + i * 8) * 64]);
        }
        if (w == 0 && lane < 16) {
            const float* gb = biask + bh * 2048 + t * 64 + lane * 4;
            GLOAD_LDS16(gb, &SM[buf ? 16512 : 16384]);
        }
    };

    stage(0, 0);
    int cur = 0;
    for (int t = 0; t < 32; ++t) {
        __syncthreads();
        if (t + 1 < 32) stage(cur ^ 1, t + 1);
        const int kO = cur ? 4096 : 0;
        const int vO = cur ? 12288 : 8192;
        const float* Bl = reinterpret_cast<const float*>(&SM[cur ? 16512 : 16384]);

        // key bias (broadcast reads); k = t2*32 + (r&3)+8*(r>>2)+4*hi
        f32x4 bb[2][4];
#pragma unroll
        for (int t2 = 0; t2 < 2; ++t2)
#pragma unroll
            for (int g2 = 0; g2 < 4; ++g2)
                bb[t2][g2] = *reinterpret_cast<const f32x4*>(Bl + t2 * 32 + g2 * 8 + hi * 4);

        f32x16 st[2][2];
#pragma unroll
        for (int qb = 0; qb < 2; ++qb)
#pragma unroll
            for (int t2 = 0; t2 < 2; ++t2)
#pragma unroll
                for (int g2 = 0; g2 < 4; ++g2)
#pragma unroll
                    for (int j = 0; j < 4; ++j) st[qb][t2][g2 * 4 + j] = bb[t2][g2][j];

        // S^T = K * Q^T : each K-frag read feeds both qb
        __builtin_amdgcn_s_setprio(1);
#pragma unroll
        for (int kc = 0; kc < 4; ++kc)
#pragma unroll
            for (int t2 = 0; t2 < 2; ++t2) {
                bf16x8 kf = *reinterpret_cast<const bf16x8*>(
                    &SM[kO + (t2 * 32 + l31) * 64 + ((((kc << 1) | hi) ^ l7) << 3)]);
                st[0][t2] = mfma32(kf, qf[0][kc], st[0][t2]);
                st[1][t2] = mfma32(kf, qf[1][kc], st[1][t2]);
            }
        __builtin_amdgcn_s_setprio(0);

        // softmax numerator: p = exp2(s), running per-lane denominator (no max needed)
#pragma unroll
        for (int qb = 0; qb < 2; ++qb) {
            float r0 = 0.f, r1 = 0.f;
#pragma unroll
            for (int i = 0; i < 16; ++i) {
                float p0 = exp2a(st[qb][0][i]); st[qb][0][i] = p0; r0 += p0;
                float p1 = exp2a(st[qb][1][i]); st[qb][1][i] = p1; r1 += p1;
            }
            lrun[qb] += r0 + r1;
        }

        // P^T -> bf16 B-frags via cvt_pk + permlane32_swap, then O^T += V^T * P^T
#pragma unroll
        for (int t2 = 0; t2 < 2; ++t2) {
            bf16x8 fA[2], fB[2];
#pragma unroll
            for (int qb = 0; qb < 2; ++qb) {
                unsigned w0 = cvtpk(st[qb][t2][0], st[qb][t2][1]);     // keys (0,1)+4hi
                unsigned w1 = cvtpk(st[qb][t2][2], st[qb][t2][3]);     // keys (2,3)+4hi
                unsigned w2 = cvtpk(st[qb][t2][4], st[qb][t2][5]);     // keys (8,9)+4hi
                unsigned w3 = cvtpk(st[qb][t2][6], st[qb][t2][7]);     // keys (10,11)+4hi
                unsigned w4 = cvtpk(st[qb][t2][8], st[qb][t2][9]);     // keys (16,17)+4hi
                unsigned w5 = cvtpk(st[qb][t2][10], st[qb][t2][11]);   // keys (18,19)+4hi
                unsigned w6 = cvtpk(st[qb][t2][12], st[qb][t2][13]);   // keys (24,25)+4hi
                unsigned w7 = cvtpk(st[qb][t2][14], st[qb][t2][15]);   // keys (26,27)+4hi
                plswap(w0, w2); plswap(w1, w3); plswap(w4, w6); plswap(w5, w7);
                u32x4 p0, p1;
                p0[0] = w0; p0[1] = w1; p0[2] = w2; p0[3] = w3;
                p1[0] = w4; p1[1] = w5; p1[2] = w6; p1[3] = w7;
                fA[qb] = __builtin_bit_cast(bf16x8, p0);
                fB[qb] = __builtin_bit_cast(bf16x8, p1);
            }
            const int kb0 = t2 * 2, kb1 = t2 * 2 + 1;
            __builtin_amdgcn_s_setprio(1);
#pragma unroll
            for (int dj = 0; dj < 2; ++dj) {
                bf16x8 v0 = *reinterpret_cast<const bf16x8*>(
                    &SM[vO + (dj * 32 + l31) * 64 + ((((kb0 << 1) | hi) ^ l7) << 3)]);
                bf16x8 v1 = *reinterpret_cast<const bf16x8*>(
                    &SM[vO + (dj * 32 + l31) * 64 + ((((kb1 << 1) | hi) ^ l7) << 3)]);
                ot[0][dj] = mfma32(v0, fA[0], ot[0][dj]);
                ot[0][dj] = mfma32(v1, fB[0], ot[0][dj]);
                ot[1][dj] = mfma32(v0, fA[1], ot[1][dj]);
                ot[1][dj] = mfma32(v1, fB[1], ot[1][dj]);
            }
            __builtin_amdgcn_s_setprio(0);
        }
        cur ^= 1;
    }

    // combine the two half-row denominators once
    lrun[0] += __shfl_xor(lrun[0], 32);
    lrun[1] += __shfl_xor(lrun[1], 32);

    __syncthreads();
    // epilogue: O^T -> LDS [256 q][72] -> coalesced global store
#pragma unroll
    for (int qb = 0; qb < 2; ++qb) {
        float inv = 1.0f / lrun[qb];
        const int base = (w * 64 + qb * 32 + l31) * 72;
#pragma unroll
        for (int dj = 0; dj < 2; ++dj)
#pragma unroll
            for (int i = 0; i < 8; ++i) {
                unsigned pr = cvtpk(ot[qb][dj][2 * i] * inv, ot[qb][dj][2 * i + 1] * inv);
                int d0 = dj * 32 + 2 * (i & 1) + 8 * (i >> 1) + 4 * hi;
                *reinterpret_cast<unsigned*>(&SM[base + d0]) = pr;
            }
    }
    __syncthreads();
    const int b = bh >> 4, h = bh & 15;
#pragma unroll
    for (int pass = 0; pass < 8; ++pass) {
        int row = pass * 32 + (tid >> 3);
        int seg = tid & 7;
        u32x4 vdat = *reinterpret_cast<const u32x4*>(&SM[row * 72 + seg * 8]);
        int l = qt * 256 + row;
        *reinterpret_cast<u32x4*>(Ob + ((size_t)b * 2048 + l) * 1024 + h * 64 + seg * 8) = vdat;
    }
}

extern "C" void kernel_launch(void* const* d_in, const int* in_sizes, int n_in,
                              void* d_out, int out_size, void* d_ws, size_t ws_size,
                              hipStream_t stream) {
    const float* query = (const float*)d_in[0];
    const float* key   = (const float*)d_in[1];
    const float* value = (const float*)d_in[2];
    const float* Wq = (const float*)d_in[3];
    const float* bq = (const float*)d_in[4];
    const float* Wk = (const float*)d_in[5];
    const float* bk = (const float*)d_in[6];
    const float* Wv = (const float*)d_in[7];
    const float* bv = (const float*)d_in[8];
    const float* Wo = (const float*)d_in[9];
    const float* bo = (const float*)d_in[10];

    unsigned short* xq = (unsigned short*)d_ws;      // 8192*1024 each
    unsigned short* xk = xq + 8388608;
    unsigned short* xv = xk + 8388608;               // reused as VbT after V-GEMM
    unsigned short* wq = xv + 8388608;               // 1024*1024 each
    unsigned short* wk = wq + 1048576;
    unsigned short* wv = wk + 1048576;
    unsigned short* wo = wv + 1048576;
    unsigned short* Qb = wo + 1048576;               // (B*H, L, 64)
    unsigned short* Kb = Qb + 8388608;
    unsigned short* Vb = Kb + 8388608;               // (B*H, L, 64)
    unsigned short* Ob = Vb + 8388608;               // (B, L, E)
    float* biask = (float*)(Ob + 8388608);           // 131072 f32
    unsigned short* VbT = xv;                        // (B*H, 64, L)

    k_cvt_all<<<dim3(1024, 7), 256, 0, stream>>>(query, key, value, Wq, Wk, Wv, Wo,
                                                 xq, xk, xv, wq, wk, wv, wo);

    k_gemm_qkv<<<1536, 256, 0, stream>>>(xq, xk, xv, wq, wk, wv,
                                         bq, bk, bv, Qb, Kb, Vb, biask);

    k_vt<<<2048, 256, 0, stream>>>(Vb, VbT);

    k_attn5<<<512, 256, 0, stream>>>(Qb, Kb, VbT, biask, Ob);

    k_gemm_out<<<512, 256, 0, stream>>>(Ob, wo, bo, (float*)d_out);
}

// Round 8
// 215.257 us; speedup vs baseline: 1.0564x; 1.0564x over previous
//
#include <hip/hip_runtime.h>
#include <hip/hip_bf16.h>
#include <stdint.h>

#define DEV __device__ __forceinline__

typedef __attribute__((ext_vector_type(8))) __bf16 bf16x8;
typedef __attribute__((ext_vector_type(4))) float f32x4;
typedef __attribute__((ext_vector_type(16))) float f32x16;
typedef __attribute__((ext_vector_type(4))) unsigned int u32x4;

#define LOG2E 1.44269504088896f

DEV unsigned short f2bf(float f) {
    union { float f; unsigned int u; } v; v.f = f;
    unsigned int u = v.u;
    return (unsigned short)((u + 0x7FFFu + ((u >> 16) & 1u)) >> 16);
}
DEV float bf2f(unsigned short s) {
    union { unsigned int u; float f; } v; v.u = ((unsigned int)s) << 16;
    return v.f;
}

DEV f32x4 mfma16(bf16x8 a, bf16x8 b, f32x4 c) {
    return __builtin_amdgcn_mfma_f32_16x16x32_bf16(a, b, c, 0, 0, 0);
}
DEV f32x16 mfma32(bf16x8 a, bf16x8 b, f32x16 c) {
    return __builtin_amdgcn_mfma_f32_32x32x16_bf16(a, b, c, 0, 0, 0);
}
DEV float exp2a(float x) { float r; asm("v_exp_f32 %0, %1" : "=v"(r) : "v"(x)); return r; }
DEV unsigned cvtpk(float lo, float hi) {
    unsigned r; asm("v_cvt_pk_bf16_f32 %0, %1, %2" : "=v"(r) : "v"(lo), "v"(hi)); return r;
}
// After call: x' = [x_lo | y_lo], y' = [x_hi | y_hi]   (lane blocks of 32) — verified R5
DEV void plswap(unsigned& x, unsigned& y) {
    asm volatile("v_permlane32_swap_b32 %0, %1" : "+v"(x), "+v"(y));
}

#define GLOAD_LDS16(g, l)                                                          \
    __builtin_amdgcn_global_load_lds((__attribute__((address_space(1))) void*)(g), \
                                     (__attribute__((address_space(3))) void*)(l), \
                                     16, 0, 0)

// ---------------- weight f32 -> bf16 converts (4 slices in one launch) ----------------
__global__ void k_cvtw(const float* __restrict__ i0, const float* __restrict__ i1,
                       const float* __restrict__ i2, const float* __restrict__ i3,
                       unsigned short* __restrict__ o0, unsigned short* __restrict__ o1,
                       unsigned short* __restrict__ o2, unsigned short* __restrict__ o3) {
    int z = blockIdx.y;
    const float* in = z == 0 ? i0 : (z == 1 ? i1 : (z == 2 ? i2 : i3));
    unsigned short* out = z == 0 ? o0 : (z == 1 ? o1 : (z == 2 ? o2 : o3));
    float scale = z == 0 ? LOG2E : 1.0f;   // fold log2e into Wq
    int stride = gridDim.x * blockDim.x;
    for (int i = blockIdx.x * blockDim.x + threadIdx.x; i * 4 < 1048576; i += stride) {
        float4 f = reinterpret_cast<const float4*>(in)[i];
        ushort4 o;
        o.x = f2bf(f.x * scale); o.y = f2bf(f.y * scale);
        o.z = f2bf(f.z * scale); o.w = f2bf(f.w * scale);
        reinterpret_cast<ushort4*>(out)[i] = o;
    }
}

// ---------------- fused QKV projection GEMM, f32-A convert-in-staging ----------------
// A = raw f32 activations (query/key/value), converted to bf16 during reg-staged
// LDS write (pipelined one K-step ahead). B = pre-converted bf16 weights via
// global_load_lds. XCD-owned (z,bm) rows: xcd=flat&7, bn=(flat>>3)&7,
// row=xcd*24+(flat>>6); z=row>>6, bm=row&63.
// z=0: Qb, bias*log2e; z=1: Kb + biask (shfl-reduced); z=2: Vb natural.
__global__ __launch_bounds__(256) void k_gemm_qkv(
    const float* __restrict__ aq, const float* __restrict__ ak, const float* __restrict__ av,
    const unsigned short* __restrict__ wq, const unsigned short* __restrict__ wk,
    const unsigned short* __restrict__ wv,
    const float* __restrict__ bq, const float* __restrict__ bk, const float* __restrict__ bv,
    unsigned short* __restrict__ Qb, unsigned short* __restrict__ Kb,
    unsigned short* __restrict__ Vb, float* __restrict__ biask) {
    __shared__ __align__(16) unsigned short As[128 * 64];
    __shared__ __align__(16) unsigned short Bs[128 * 64];
    const int flat = blockIdx.x;
    const int xcd = flat & 7;
    const int bn = (flat >> 3) & 7;
    const int row = xcd * 24 + (flat >> 6);
    const int z = row >> 6;
    const int bm = row & 63;

    const float* A = z == 0 ? aq : (z == 1 ? ak : av);
    const unsigned short* Bw = z == 0 ? wq : (z == 1 ? wk : wv);
    const float* bias = z == 0 ? bq : (z == 1 ? bk : bv);
    const float bscale = z == 0 ? LOG2E : 1.0f;
    const int K = 1024;

    const int tid = threadIdx.x;
    const int lane = tid & 63, w = tid >> 6;
    const int g = lane >> 4, cc = lane & 15;
    const int wm = w >> 1, wn = w & 1;

    f32x4 acc[4][4] = {};
    const int srow = lane >> 3;
    const int scol = (lane & 7) * 8;

    // A reg-staging (f32 -> regs), one K-step ahead
    float4 ar[4][2];
    auto loadA = [&](int kt) {
#pragma unroll
        for (int p = 0; p < 4; ++p) {
            int c = w * 4 + p;
            int rr = c * 8 + srow;
            const float* gA = A + (size_t)(bm * 128 + rr) * K + kt + scol;
            ar[p][0] = *reinterpret_cast<const float4*>(gA);
            ar[p][1] = *reinterpret_cast<const float4*>(gA + 4);
        }
    };
    auto writeA = [&]() {   // convert + ds_write to the exact slots gload_lds used
#pragma unroll
        for (int p = 0; p < 4; ++p) {
            int c = w * 4 + p;
            u32x4 pk;
            pk[0] = cvtpk(ar[p][0].x, ar[p][0].y);
            pk[1] = cvtpk(ar[p][0].z, ar[p][0].w);
            pk[2] = cvtpk(ar[p][1].x, ar[p][1].y);
            pk[3] = cvtpk(ar[p][1].z, ar[p][1].w);
            *reinterpret_cast<u32x4*>(&As[c * 512 + srow * 64 + scol]) = pk;
        }
    };

    loadA(0);
    for (int kt = 0; kt < K; kt += 64) {
        writeA();
#pragma unroll
        for (int p = 0; p < 4; ++p) {
            int c = w * 4 + p;
            int rr = c * 8 + srow;
            const unsigned short* gB = Bw + (size_t)(bn * 128 + rr) * K + kt + scol;
            GLOAD_LDS16(gB, &Bs[c * 512]);
        }
        __syncthreads();
        if (kt + 64 < K) loadA(kt + 64);   // issue early; drains under/after compute
#pragma unroll
        for (int kc = 0; kc < 2; ++kc) {
            bf16x8 af[4], bf[4];
#pragma unroll
            for (int i = 0; i < 4; ++i) {
                af[i] = *reinterpret_cast<const bf16x8*>(&As[(wm * 64 + i * 16 + cc) * 64 + kc * 32 + g * 8]);
                bf[i] = *reinterpret_cast<const bf16x8*>(&Bs[(wn * 64 + i * 16 + cc) * 64 + kc * 32 + g * 8]);
            }
#pragma unroll
            for (int mi = 0; mi < 4; ++mi)
#pragma unroll
                for (int nj = 0; nj < 4; ++nj)
                    acc[mi][nj] = mfma16(af[mi], bf[nj], acc[mi][nj]);
        }
        __syncthreads();
    }

    unsigned short* out = z == 0 ? Qb : (z == 1 ? Kb : Vb);
    float sq[4][4];
#pragma unroll
    for (int mi = 0; mi < 4; ++mi)
#pragma unroll
        for (int r = 0; r < 4; ++r) sq[mi][r] = 0.f;

#pragma unroll
    for (int mi = 0; mi < 4; ++mi) {
#pragma unroll
        for (int nj = 0; nj < 4; ++nj) {
            int n = bn * 128 + wn * 64 + nj * 16 + cc;
            float bvv = bias[n] * bscale;
            int h = n >> 6, d = n & 63;
#pragma unroll
            for (int r = 0; r < 4; ++r) {
                int m = bm * 128 + wm * 64 + mi * 16 + g * 4 + r;
                unsigned short us = f2bf(acc[mi][nj][r] + bvv);
                int b = m >> 11, l = m & 2047;
                out[(((size_t)b * 16 + h) * 2048 + l) * 64 + d] = us;
                if (z == 1) { float vr = bf2f(us); sq[mi][r] += vr * vr; }
            }
        }
    }
    if (z == 1) {
        const int h = bn * 2 + wn;
#pragma unroll
        for (int mi = 0; mi < 4; ++mi)
#pragma unroll
            for (int r = 0; r < 4; ++r) {
                float s = sq[mi][r];
                s += __shfl_xor(s, 1); s += __shfl_xor(s, 2);
                s += __shfl_xor(s, 4); s += __shfl_xor(s, 8);
                if (cc == 0) {
                    int m = bm * 128 + wm * 64 + mi * 16 + g * 4 + r;
                    biask[(((size_t)(m >> 11)) * 16 + h) * 2048 + (m & 2047)] =
                        -0.5f * LOG2E * s;
                }
            }
    }
}

// ---------------- V transpose: (BH, L, 64) -> (BH, 64, L) ----------------
__global__ __launch_bounds__(256) void k_vt(const unsigned short* __restrict__ Vb,
                                            unsigned short* __restrict__ VbT) {
    __shared__ __align__(16) unsigned short T[64 * 72];
    const int blk = blockIdx.x;
    const int bh = blk >> 5, lt = blk & 31;
    const int tid = threadIdx.x;
    const int rr = tid >> 3, seg = tid & 7;
#pragma unroll
    for (int p = 0; p < 2; ++p) {
        int row = p * 32 + rr;
        const unsigned short* src = Vb + ((size_t)bh * 2048 + lt * 64 + row) * 64 + seg * 8;
        *reinterpret_cast<u32x4*>(&T[row * 72 + seg * 8]) = *reinterpret_cast<const u32x4*>(src);
    }
    __syncthreads();
#pragma unroll
    for (int p = 0; p < 2; ++p) {
        int d = p * 32 + rr;
        union { u32x4 v; unsigned short s[8]; } o;
#pragma unroll
        for (int j = 0; j < 8; ++j) o.s[j] = T[(seg * 8 + j) * 72 + d];
        unsigned short* dst = VbT + ((size_t)bh * 64 + d) * 2048 + lt * 64 + seg * 8;
        *reinterpret_cast<u32x4*>(dst) = o.v;
    }
}

// ---------------- final GEMM: d_out = Ob * Wo^T + bo (f32 out), XCD-remapped ----------------
__global__ __launch_bounds__(256) void k_gemm_out(const unsigned short* __restrict__ A,
                                                  const unsigned short* __restrict__ Bw,
                                                  const float* __restrict__ bias,
                                                  float* __restrict__ out) {
    __shared__ __align__(16) unsigned short As[128 * 64];
    __shared__ __align__(16) unsigned short Bs[128 * 64];
    const int K = 1024, N = 1024;
    const int flat = blockIdx.x;
    const int xcd = flat & 7;
    const int bn = (flat >> 3) & 7;
    const int bm = xcd * 8 + (flat >> 6);

    const int tid = threadIdx.x;
    const int lane = tid & 63, w = tid >> 6;
    const int g = lane >> 4, cc = lane & 15;
    const int wm = w >> 1, wn = w & 1;

    f32x4 acc[4][4] = {};
    const int srow = lane >> 3;
    const int scol = (lane & 7) * 8;

    for (int kt = 0; kt < K; kt += 64) {
#pragma unroll
        for (int p = 0; p < 4; ++p) {
            int c = w * 4 + p;
            int rr = c * 8 + srow;
            const unsigned short* gA = A + (size_t)(bm * 128 + rr) * K + kt + scol;
            GLOAD_LDS16(gA, &As[c * 512]);
            const unsigned short* gB = Bw + (size_t)(bn * 128 + rr) * K + kt + scol;
            GLOAD_LDS16(gB, &Bs[c * 512]);
        }
        __syncthreads();
#pragma unroll
        for (int kc = 0; kc < 2; ++kc) {
            bf16x8 af[4], bf[4];
#pragma unroll
            for (int i = 0; i < 4; ++i) {
                af[i] = *reinterpret_cast<const bf16x8*>(&As[(wm * 64 + i * 16 + cc) * 64 + kc * 32 + g * 8]);
                bf[i] = *reinterpret_cast<const bf16x8*>(&Bs[(wn * 64 + i * 16 + cc) * 64 + kc * 32 + g * 8]);
            }
#pragma unroll
            for (int mi = 0; mi < 4; ++mi)
#pragma unroll
                for (int nj = 0; nj < 4; ++nj)
                    acc[mi][nj] = mfma16(af[mi], bf[nj], acc[mi][nj]);
        }
        __syncthreads();
    }

#pragma unroll
    for (int mi = 0; mi < 4; ++mi) {
#pragma unroll
        for (int nj = 0; nj < 4; ++nj) {
            int n = bn * 128 + wn * 64 + nj * 16 + cc;
            float bvv = bias[n];
#pragma unroll
            for (int r = 0; r < 4; ++r) {
                int m = bm * 128 + wm * 64 + mi * 16 + g * 4 + r;
                out[(size_t)m * N + n] = acc[mi][nj][r] + bvv;
            }
        }
    }
}

// ---------------- flash attention: RBF scores bounded => NO online max ----------------
// p = exp2((qk - 0.5||k||^2) log2e); the -0.5||q||^2 row-constant cancels in softmax.
// Q (BH,L,64) bf16 pre-scaled by log2e; K (BH,L,64); VT (BH,64,L); biask = -0.5*log2e*||k||^2.
__global__ __launch_bounds__(256, 2) void k_attn5(const unsigned short* __restrict__ Q,
                                                  const unsigned short* __restrict__ K,
                                                  const unsigned short* __restrict__ VT,
                                                  const float* __restrict__ biask,
                                                  unsigned short* __restrict__ Ob) {
    // ushort offsets: K0=0, K1=4096, V0=8192, V1=12288, B0=16384, B1=16512.
    // Epilogue reuses [0, 18432) as 256x72 staging.
    __shared__ __align__(16) unsigned short SM[18432];
    const int tid = threadIdx.x;
    const int lane = tid & 63, w = tid >> 6;
    const int l31 = lane & 31, hi = lane >> 5, l7 = lane & 7;
    const int flat = blockIdx.x;
    const int bh = (flat & 7) * 8 + ((flat >> 3) & 7);   // XCD-locality remap (bijective)
    const int qt = flat >> 6;                            // 0..7 (256 queries per block)
    const size_t kvbase = (size_t)bh * 2048 * 64;
    const int q0 = qt * 256 + w * 64;

    // Q fragments (B-operand), two 32-query sub-blocks per wave
    bf16x8 qf[2][4];
#pragma unroll
    for (int qb = 0; qb < 2; ++qb)
#pragma unroll
        for (int kc = 0; kc < 4; ++kc)
            qf[qb][kc] = *reinterpret_cast<const bf16x8*>(
                Q + kvbase + (size_t)(q0 + qb * 32 + l31) * 64 + kc * 16 + hi * 8);

    f32x16 ot[2][2] = {};
    float lrun[2] = {0.f, 0.f};
    const int srow = lane >> 3;

    auto stage = [&](int buf, int t) {
        const int kO = buf ? 4096 : 0;
        const int vO = buf ? 12288 : 8192;
#pragma unroll
        for (int i = 0; i < 2; ++i) {
            int r = w * 16 + i * 8 + srow;
            int cb = l7 ^ (r & 7);   // pre-swizzled source -> linear LDS == swizzled layout
            const unsigned short* gk = K + kvbase + (size_t)(t * 64 + r) * 64 + cb * 8;
            GLOAD_LDS16(gk, &SM[kO + (w * 16 + i * 8) * 64]);
            const unsigned short* gv = VT + kvbase + (size_t)r * 2048 + t * 64 + cb * 8;
            GLOAD_LDS16(gv, &SM[vO + (w * 16 + i * 8) * 64]);
        }
        if (w == 0 && lane < 16) {
            const float* gb = biask + bh * 2048 + t * 64 + lane * 4;
            GLOAD_LDS16(gb, &SM[buf ? 16512 : 16384]);
        }
    };

    stage(0, 0);
    int cur = 0;
    for (int t = 0; t < 32; ++t) {
        __syncthreads();
        if (t + 1 < 32) stage(cur ^ 1, t + 1);
        const int kO = cur ? 4096 : 0;
        const int vO = cur ? 12288 : 8192;
        const float* Bl = reinterpret_cast<const float*>(&SM[cur ? 16512 : 16384]);

        // key bias (broadcast reads); k = t2*32 + (r&3)+8*(r>>2)+4*hi
        f32x4 bb[2][4];
#pragma unroll
        for (int t2 = 0; t2 < 2; ++t2)
#pragma unroll
            for (int g2 = 0; g2 < 4; ++g2)
                bb[t2][g2] = *reinterpret_cast<const f32x4*>(Bl + t2 * 32 + g2 * 8 + hi * 4);

        f32x16 st[2][2];
#pragma unroll
        for (int qb = 0; qb < 2; ++qb)
#pragma unroll
            for (int t2 = 0; t2 < 2; ++t2)
#pragma unroll
                for (int g2 = 0; g2 < 4; ++g2)
#pragma unroll
                    for (int j = 0; j < 4; ++j) st[qb][t2][g2 * 4 + j] = bb[t2][g2][j];

        // S^T = K * Q^T : each K-frag read feeds both qb
        __builtin_amdgcn_s_setprio(1);
#pragma unroll
        for (int kc = 0; kc < 4; ++kc)
#pragma unroll
            for (int t2 = 0; t2 < 2; ++t2) {
                bf16x8 kf = *reinterpret_cast<const bf16x8*>(
                    &SM[kO + (t2 * 32 + l31) * 64 + ((((kc << 1) | hi) ^ l7) << 3)]);
                st[0][t2] = mfma32(kf, qf[0][kc], st[0][t2]);
                st[1][t2] = mfma32(kf, qf[1][kc], st[1][t2]);
            }
        __builtin_amdgcn_s_setprio(0);

        // softmax numerator: p = exp2(s), running per-lane denominator (no max needed)
#pragma unroll
        for (int qb = 0; qb < 2; ++qb) {
            float r0 = 0.f, r1 = 0.f;
#pragma unroll
            for (int i = 0; i < 16; ++i) {
                float p0 = exp2a(st[qb][0][i]); st[qb][0][i] = p0; r0 += p0;
                float p1 = exp2a(st[qb][1][i]); st[qb][1][i] = p1; r1 += p1;
            }
            lrun[qb] += r0 + r1;
        }

        // P^T -> bf16 B-frags via cvt_pk + permlane32_swap, then O^T += V^T * P^T
#pragma unroll
        for (int t2 = 0; t2 < 2; ++t2) {
            bf16x8 fA[2], fB[2];
#pragma unroll
            for (int qb = 0; qb < 2; ++qb) {
                unsigned w0 = cvtpk(st[qb][t2][0], st[qb][t2][1]);     // keys (0,1)+4hi
                unsigned w1 = cvtpk(st[qb][t2][2], st[qb][t2][3]);     // keys (2,3)+4hi
                unsigned w2 = cvtpk(st[qb][t2][4], st[qb][t2][5]);     // keys (8,9)+4hi
                unsigned w3 = cvtpk(st[qb][t2][6], st[qb][t2][7]);     // keys (10,11)+4hi
                unsigned w4 = cvtpk(st[qb][t2][8], st[qb][t2][9]);     // keys (16,17)+4hi
                unsigned w5 = cvtpk(st[qb][t2][10], st[qb][t2][11]);   // keys (18,19)+4hi
                unsigned w6 = cvtpk(st[qb][t2][12], st[qb][t2][13]);   // keys (24,25)+4hi
                unsigned w7 = cvtpk(st[qb][t2][14], st[qb][t2][15]);   // keys (26,27)+4hi
                plswap(w0, w2); plswap(w1, w3); plswap(w4, w6); plswap(w5, w7);
                u32x4 p0, p1;
                p0[0] = w0; p0[1] = w1; p0[2] = w2; p0[3] = w3;
                p1[0] = w4; p1[1] = w5; p1[2] = w6; p1[3] = w7;
                fA[qb] = __builtin_bit_cast(bf16x8, p0);
                fB[qb] = __builtin_bit_cast(bf16x8, p1);
            }
            const int kb0 = t2 * 2, kb1 = t2 * 2 + 1;
            __builtin_amdgcn_s_setprio(1);
#pragma unroll
            for (int dj = 0; dj < 2; ++dj) {
                bf16x8 v0 = *reinterpret_cast<const bf16x8*>(
                    &SM[vO + (dj * 32 + l31) * 64 + ((((kb0 << 1) | hi) ^ l7) << 3)]);
                bf16x8 v1 = *reinterpret_cast<const bf16x8*>(
                    &SM[vO + (dj * 32 + l31) * 64 + ((((kb1 << 1) | hi) ^ l7) << 3)]);
                ot[0][dj] = mfma32(v0, fA[0], ot[0][dj]);
                ot[0][dj] = mfma32(v1, fB[0], ot[0][dj]);
                ot[1][dj] = mfma32(v0, fA[1], ot[1][dj]);
                ot[1][dj] = mfma32(v1, fB[1], ot[1][dj]);
            }
            __builtin_amdgcn_s_setprio(0);
        }
        cur ^= 1;
    }

    // combine the two half-row denominators once
    lrun[0] += __shfl_xor(lrun[0], 32);
    lrun[1] += __shfl_xor(lrun[1], 32);

    __syncthreads();
    // epilogue: O^T -> LDS [256 q][72] -> coalesced global store
#pragma unroll
    for (int qb = 0; qb < 2; ++qb) {
        float inv = 1.0f / lrun[qb];
        const int base = (w * 64 + qb * 32 + l31) * 72;
#pragma unroll
        for (int dj = 0; dj < 2; ++dj)
#pragma unroll
            for (int i = 0; i < 8; ++i) {
                unsigned pr = cvtpk(ot[qb][dj][2 * i] * inv, ot[qb][dj][2 * i + 1] * inv);
                int d0 = dj * 32 + 2 * (i & 1) + 8 * (i >> 1) + 4 * hi;
                *reinterpret_cast<unsigned*>(&SM[base + d0]) = pr;
            }
    }
    __syncthreads();
    const int b = bh >> 4, h = bh & 15;
#pragma unroll
    for (int pass = 0; pass < 8; ++pass) {
        int row = pass * 32 + (tid >> 3);
        int seg = tid & 7;
        u32x4 vdat = *reinterpret_cast<const u32x4*>(&SM[row * 72 + seg * 8]);
        int l = qt * 256 + row;
        *reinterpret_cast<u32x4*>(Ob + ((size_t)b * 2048 + l) * 1024 + h * 64 + seg * 8) = vdat;
    }
}

extern "C" void kernel_launch(void* const* d_in, const int* in_sizes, int n_in,
                              void* d_out, int out_size, void* d_ws, size_t ws_size,
                              hipStream_t stream) {
    const float* query = (const float*)d_in[0];
    const float* key   = (const float*)d_in[1];
    const float* value = (const float*)d_in[2];
    const float* Wq = (const float*)d_in[3];
    const float* bq = (const float*)d_in[4];
    const float* Wk = (const float*)d_in[5];
    const float* bk = (const float*)d_in[6];
    const float* Wv = (const float*)d_in[7];
    const float* bv = (const float*)d_in[8];
    const float* Wo = (const float*)d_in[9];
    const float* bo = (const float*)d_in[10];

    unsigned short* VbT = (unsigned short*)d_ws;     // (B*H, 64, L)
    unsigned short* wq = VbT + 8388608;              // 1024*1024 each
    unsigned short* wk = wq + 1048576;
    unsigned short* wv = wk + 1048576;
    unsigned short* wo = wv + 1048576;
    unsigned short* Qb = wo + 1048576;               // (B*H, L, 64)
    unsigned short* Kb = Qb + 8388608;
    unsigned short* Vb = Kb + 8388608;               // (B*H, L, 64)
    unsigned short* Ob = Vb + 8388608;               // (B, L, E)
    float* biask = (float*)(Ob + 8388608);           // 131072 f32

    k_cvtw<<<dim3(256, 4), 256, 0, stream>>>(Wq, Wk, Wv, Wo, wq, wk, wv, wo);

    k_gemm_qkv<<<1536, 256, 0, stream>>>(query, key, value, wq, wk, wv,
                                         bq, bk, bv, Qb, Kb, Vb, biask);

    k_vt<<<2048, 256, 0, stream>>>(Vb, VbT);

    k_attn5<<<512, 256, 0, stream>>>(Qb, Kb, VbT, biask, Ob);

    k_gemm_out<<<512, 256, 0, stream>>>(Ob, wo, bo, (float*)d_out);
}

// Round 9
// 213.854 us; speedup vs baseline: 1.0634x; 1.0066x over previous
//
#include <hip/hip_runtime.h>
#include <hip/hip_bf16.h>
#include <stdint.h>

#define DEV __device__ __forceinline__

typedef __attribute__((ext_vector_type(8))) __bf16 bf16x8;
typedef __attribute__((ext_vector_type(4))) float f32x4;
typedef __attribute__((ext_vector_type(16))) float f32x16;
typedef __attribute__((ext_vector_type(4))) unsigned int u32x4;

#define LOG2E 1.44269504088896f

DEV unsigned short f2bf(float f) {
    union { float f; unsigned int u; } v; v.f = f;
    unsigned int u = v.u;
    return (unsigned short)((u + 0x7FFFu + ((u >> 16) & 1u)) >> 16);
}
DEV float bf2f(unsigned short s) {
    union { unsigned int u; float f; } v; v.u = ((unsigned int)s) << 16;
    return v.f;
}

DEV f32x4 mfma16(bf16x8 a, bf16x8 b, f32x4 c) {
    return __builtin_amdgcn_mfma_f32_16x16x32_bf16(a, b, c, 0, 0, 0);
}
DEV f32x16 mfma32(bf16x8 a, bf16x8 b, f32x16 c) {
    return __builtin_amdgcn_mfma_f32_32x32x16_bf16(a, b, c, 0, 0, 0);
}
DEV float exp2a(float x) { float r; asm("v_exp_f32 %0, %1" : "=v"(r) : "v"(x)); return r; }
DEV unsigned cvtpk(float lo, float hi) {
    unsigned r; asm("v_cvt_pk_bf16_f32 %0, %1, %2" : "=v"(r) : "v"(lo), "v"(hi)); return r;
}
// After call: x' = [x_lo | y_lo], y' = [x_hi | y_hi]   (lane blocks of 32) — verified R5
DEV void plswap(unsigned& x, unsigned& y) {
    asm volatile("v_permlane32_swap_b32 %0, %1" : "+v"(x), "+v"(y));
}

#define GLOAD_LDS16(g, l)                                                          \
    __builtin_amdgcn_global_load_lds((__attribute__((address_space(1))) void*)(g), \
                                     (__attribute__((address_space(3))) void*)(l), \
                                     16, 0, 0)

// ---------------- weight f32 -> bf16 converts (4 slices in one launch) ----------------
__global__ void k_cvtw(const float* __restrict__ i0, const float* __restrict__ i1,
                       const float* __restrict__ i2, const float* __restrict__ i3,
                       unsigned short* __restrict__ o0, unsigned short* __restrict__ o1,
                       unsigned short* __restrict__ o2, unsigned short* __restrict__ o3) {
    int z = blockIdx.y;
    const float* in = z == 0 ? i0 : (z == 1 ? i1 : (z == 2 ? i2 : i3));
    unsigned short* out = z == 0 ? o0 : (z == 1 ? o1 : (z == 2 ? o2 : o3));
    float scale = z == 0 ? LOG2E : 1.0f;   // fold log2e into Wq
    int stride = gridDim.x * blockDim.x;
    for (int i = blockIdx.x * blockDim.x + threadIdx.x; i * 4 < 1048576; i += stride) {
        float4 f = reinterpret_cast<const float4*>(in)[i];
        ushort4 o;
        o.x = f2bf(f.x * scale); o.y = f2bf(f.y * scale);
        o.z = f2bf(f.z * scale); o.w = f2bf(f.w * scale);
        reinterpret_cast<ushort4*>(out)[i] = o;
    }
}

// ---------------- fused QKV projection GEMM, f32-A convert-in-staging ----------------
// A = raw f32 activations, converted in reg-staged LDS write. A-loads for kt+64 are
// issued BEFORE the top barrier so A+B latencies share ONE vmcnt(0) drain window
// (R8's post-barrier issue created a second full-latency stall at the bottom barrier).
// XCD-owned (z,bm) rows: xcd=flat&7, bn=(flat>>3)&7, row=xcd*24+(flat>>6).
// z=0: Qb, bias*log2e; z=1: Kb + biask (shfl-reduced); z=2: Vb natural.
__global__ __launch_bounds__(256) void k_gemm_qkv(
    const float* __restrict__ aq, const float* __restrict__ ak, const float* __restrict__ av,
    const unsigned short* __restrict__ wq, const unsigned short* __restrict__ wk,
    const unsigned short* __restrict__ wv,
    const float* __restrict__ bq, const float* __restrict__ bk, const float* __restrict__ bv,
    unsigned short* __restrict__ Qb, unsigned short* __restrict__ Kb,
    unsigned short* __restrict__ Vb, float* __restrict__ biask) {
    __shared__ __align__(16) unsigned short As[128 * 64];
    __shared__ __align__(16) unsigned short Bs[128 * 64];
    const int flat = blockIdx.x;
    const int xcd = flat & 7;
    const int bn = (flat >> 3) & 7;
    const int row = xcd * 24 + (flat >> 6);
    const int z = row >> 6;
    const int bm = row & 63;

    const float* A = z == 0 ? aq : (z == 1 ? ak : av);
    const unsigned short* Bw = z == 0 ? wq : (z == 1 ? wk : wv);
    const float* bias = z == 0 ? bq : (z == 1 ? bk : bv);
    const float bscale = z == 0 ? LOG2E : 1.0f;
    const int K = 1024;

    const int tid = threadIdx.x;
    const int lane = tid & 63, w = tid >> 6;
    const int g = lane >> 4, cc = lane & 15;
    const int wm = w >> 1, wn = w & 1;

    f32x4 acc[4][4] = {};
    const int srow = lane >> 3;
    const int scol = (lane & 7) * 8;

    // A reg-staging (f32 -> regs), one K-step ahead
    float4 ar[4][2];
    auto loadA = [&](int kt) {
#pragma unroll
        for (int p = 0; p < 4; ++p) {
            int c = w * 4 + p;
            int rr = c * 8 + srow;
            const float* gA = A + (size_t)(bm * 128 + rr) * K + kt + scol;
            ar[p][0] = *reinterpret_cast<const float4*>(gA);
            ar[p][1] = *reinterpret_cast<const float4*>(gA + 4);
        }
    };
    auto writeA = [&]() {   // convert + ds_write to the exact slots gload_lds used
#pragma unroll
        for (int p = 0; p < 4; ++p) {
            int c = w * 4 + p;
            u32x4 pk;
            pk[0] = cvtpk(ar[p][0].x, ar[p][0].y);
            pk[1] = cvtpk(ar[p][0].z, ar[p][0].w);
            pk[2] = cvtpk(ar[p][1].x, ar[p][1].y);
            pk[3] = cvtpk(ar[p][1].z, ar[p][1].w);
            *reinterpret_cast<u32x4*>(&As[c * 512 + srow * 64 + scol]) = pk;
        }
    };

    loadA(0);
    for (int kt = 0; kt < K; kt += 64) {
        writeA();                          // consumes ar(kt); waits A-loads (prologue only)
        if (kt + 64 < K) loadA(kt + 64);   // issue early: shares barrier#1's drain with B
#pragma unroll
        for (int p = 0; p < 4; ++p) {
            int c = w * 4 + p;
            int rr = c * 8 + srow;
            const unsigned short* gB = Bw + (size_t)(bn * 128 + rr) * K + kt + scol;
            GLOAD_LDS16(gB, &Bs[c * 512]);
        }
        __syncthreads();                   // single vmcnt(0) drain: A(kt+64) + B(kt)
#pragma unroll
        for (int kc = 0; kc < 2; ++kc) {
            bf16x8 af[4], bf[4];
#pragma unroll
            for (int i = 0; i < 4; ++i) {
                af[i] = *reinterpret_cast<const bf16x8*>(&As[(wm * 64 + i * 16 + cc) * 64 + kc * 32 + g * 8]);
                bf[i] = *reinterpret_cast<const bf16x8*>(&Bs[(wn * 64 + i * 16 + cc) * 64 + kc * 32 + g * 8]);
            }
#pragma unroll
            for (int mi = 0; mi < 4; ++mi)
#pragma unroll
                for (int nj = 0; nj < 4; ++nj)
                    acc[mi][nj] = mfma16(af[mi], bf[nj], acc[mi][nj]);
        }
        __syncthreads();                   // nothing outstanding here
    }

    unsigned short* out = z == 0 ? Qb : (z == 1 ? Kb : Vb);
    float sq[4][4];
#pragma unroll
    for (int mi = 0; mi < 4; ++mi)
#pragma unroll
        for (int r = 0; r < 4; ++r) sq[mi][r] = 0.f;

#pragma unroll
    for (int mi = 0; mi < 4; ++mi) {
#pragma unroll
        for (int nj = 0; nj < 4; ++nj) {
            int n = bn * 128 + wn * 64 + nj * 16 + cc;
            float bvv = bias[n] * bscale;
            int h = n >> 6, d = n & 63;
#pragma unroll
            for (int r = 0; r < 4; ++r) {
                int m = bm * 128 + wm * 64 + mi * 16 + g * 4 + r;
                unsigned short us = f2bf(acc[mi][nj][r] + bvv);
                int b = m >> 11, l = m & 2047;
                out[(((size_t)b * 16 + h) * 2048 + l) * 64 + d] = us;
                if (z == 1) { float vr = bf2f(us); sq[mi][r] += vr * vr; }
            }
        }
    }
    if (z == 1) {
        const int h = bn * 2 + wn;
#pragma unroll
        for (int mi = 0; mi < 4; ++mi)
#pragma unroll
            for (int r = 0; r < 4; ++r) {
                float s = sq[mi][r];
                s += __shfl_xor(s, 1); s += __shfl_xor(s, 2);
                s += __shfl_xor(s, 4); s += __shfl_xor(s, 8);
                if (cc == 0) {
                    int m = bm * 128 + wm * 64 + mi * 16 + g * 4 + r;
                    biask[(((size_t)(m >> 11)) * 16 + h) * 2048 + (m & 2047)] =
                        -0.5f * LOG2E * s;
                }
            }
    }
}

// ---------------- V transpose: (BH, L, 64) -> (BH, 64, L) ----------------
__global__ __launch_bounds__(256) void k_vt(const unsigned short* __restrict__ Vb,
                                            unsigned short* __restrict__ VbT) {
    __shared__ __align__(16) unsigned short T[64 * 72];
    const int blk = blockIdx.x;
    const int bh = blk >> 5, lt = blk & 31;
    const int tid = threadIdx.x;
    const int rr = tid >> 3, seg = tid & 7;
#pragma unroll
    for (int p = 0; p < 2; ++p) {
        int row = p * 32 + rr;
        const unsigned short* src = Vb + ((size_t)bh * 2048 + lt * 64 + row) * 64 + seg * 8;
        *reinterpret_cast<u32x4*>(&T[row * 72 + seg * 8]) = *reinterpret_cast<const u32x4*>(src);
    }
    __syncthreads();
#pragma unroll
    for (int p = 0; p < 2; ++p) {
        int d = p * 32 + rr;
        union { u32x4 v; unsigned short s[8]; } o;
#pragma unroll
        for (int j = 0; j < 8; ++j) o.s[j] = T[(seg * 8 + j) * 72 + d];
        unsigned short* dst = VbT + ((size_t)bh * 64 + d) * 2048 + lt * 64 + seg * 8;
        *reinterpret_cast<u32x4*>(dst) = o.v;
    }
}

// ---------------- final GEMM: d_out = Ob * Wo^T + bo (f32 out), XCD-remapped ----------------
__global__ __launch_bounds__(256) void k_gemm_out(const unsigned short* __restrict__ A,
                                                  const unsigned short* __restrict__ Bw,
                                                  const float* __restrict__ bias,
                                                  float* __restrict__ out) {
    __shared__ __align__(16) unsigned short As[128 * 64];
    __shared__ __align__(16) unsigned short Bs[128 * 64];
    const int K = 1024, N = 1024;
    const int flat = blockIdx.x;
    const int xcd = flat & 7;
    const int bn = (flat >> 3) & 7;
    const int bm = xcd * 8 + (flat >> 6);

    const int tid = threadIdx.x;
    const int lane = tid & 63, w = tid >> 6;
    const int g = lane >> 4, cc = lane & 15;
    const int wm = w >> 1, wn = w & 1;

    f32x4 acc[4][4] = {};
    const int srow = lane >> 3;
    const int scol = (lane & 7) * 8;

    for (int kt = 0; kt < K; kt += 64) {
#pragma unroll
        for (int p = 0; p < 4; ++p) {
            int c = w * 4 + p;
            int rr = c * 8 + srow;
            const unsigned short* gA = A + (size_t)(bm * 128 + rr) * K + kt + scol;
            GLOAD_LDS16(gA, &As[c * 512]);
            const unsigned short* gB = Bw + (size_t)(bn * 128 + rr) * K + kt + scol;
            GLOAD_LDS16(gB, &Bs[c * 512]);
        }
        __syncthreads();
#pragma unroll
        for (int kc = 0; kc < 2; ++kc) {
            bf16x8 af[4], bf[4];
#pragma unroll
            for (int i = 0; i < 4; ++i) {
                af[i] = *reinterpret_cast<const bf16x8*>(&As[(wm * 64 + i * 16 + cc) * 64 + kc * 32 + g * 8]);
                bf[i] = *reinterpret_cast<const bf16x8*>(&Bs[(wn * 64 + i * 16 + cc) * 64 + kc * 32 + g * 8]);
            }
#pragma unroll
            for (int mi = 0; mi < 4; ++mi)
#pragma unroll
                for (int nj = 0; nj < 4; ++nj)
                    acc[mi][nj] = mfma16(af[mi], bf[nj], acc[mi][nj]);
        }
        __syncthreads();
    }

#pragma unroll
    for (int mi = 0; mi < 4; ++mi) {
#pragma unroll
        for (int nj = 0; nj < 4; ++nj) {
            int n = bn * 128 + wn * 64 + nj * 16 + cc;
            float bvv = bias[n];
#pragma unroll
            for (int r = 0; r < 4; ++r) {
                int m = bm * 128 + wm * 64 + mi * 16 + g * 4 + r;
                out[(size_t)m * N + n] = acc[mi][nj][r] + bvv;
            }
        }
    }
}

// ---------------- flash attention: RBF scores bounded => NO online max ----------------
// p = exp2((qk - 0.5||k||^2) log2e); the -0.5||q||^2 row-constant cancels in softmax.
// Q (BH,L,64) bf16 pre-scaled by log2e; K (BH,L,64); VT (BH,64,L); biask = -0.5*log2e*||k||^2.
__global__ __launch_bounds__(256, 2) void k_attn5(const unsigned short* __restrict__ Q,
                                                  const unsigned short* __restrict__ K,
                                                  const unsigned short* __restrict__ VT,
                                                  const float* __restrict__ biask,
                                                  unsigned short* __restrict__ Ob) {
    // ushort offsets: K0=0, K1=4096, V0=8192, V1=12288, B0=16384, B1=16512.
    // Epilogue reuses [0, 18432) as 256x72 staging.
    __shared__ __align__(16) unsigned short SM[18432];
    const int tid = threadIdx.x;
    const int lane = tid & 63, w = tid >> 6;
    const int l31 = lane & 31, hi = lane >> 5, l7 = lane & 7;
    const int flat = blockIdx.x;
    const int bh = (flat & 7) * 8 + ((flat >> 3) & 7);   // XCD-locality remap (bijective)
    const int qt = flat >> 6;                            // 0..7 (256 queries per block)
    const size_t kvbase = (size_t)bh * 2048 * 64;
    const int q0 = qt * 256 + w * 64;

    // Q fragments (B-operand), two 32-query sub-blocks per wave
    bf16x8 qf[2][4];
#pragma unroll
    for (int qb = 0; qb < 2; ++qb)
#pragma unroll
        for (int kc = 0; kc < 4; ++kc)
            qf[qb][kc] = *reinterpret_cast<const bf16x8*>(
                Q + kvbase + (size_t)(q0 + qb * 32 + l31) * 64 + kc * 16 + hi * 8);

    f32x16 ot[2][2] = {};
    float lrun[2] = {0.f, 0.f};
    const int srow = lane >> 3;

    auto stage = [&](int buf, int t) {
        const int kO = buf ? 4096 : 0;
        const int vO = buf ? 12288 : 8192;
#pragma unroll
        for (int i = 0; i < 2; ++i) {
            int r = w * 16 + i * 8 + srow;
            int cb = l7 ^ (r & 7);   // pre-swizzled source -> linear LDS == swizzled layout
            const unsigned short* gk = K + kvbase + (size_t)(t * 64 + r) * 64 + cb * 8;
            GLOAD_LDS16(gk, &SM[kO + (w * 16 + i * 8) * 64]);
            const unsigned short* gv = VT + kvbase + (size_t)r * 2048 + t * 64 + cb * 8;
            GLOAD_LDS16(gv, &SM[vO + (w * 16 + i * 8) * 64]);
        }
        if (w == 0 && lane < 16) {
            const float* gb = biask + bh * 2048 + t * 64 + lane * 4;
            GLOAD_LDS16(gb, &SM[buf ? 16512 : 16384]);
        }
    };

    stage(0, 0);
    int cur = 0;
    for (int t = 0; t < 32; ++t) {
        __syncthreads();
        if (t + 1 < 32) stage(cur ^ 1, t + 1);
        const int kO = cur ? 4096 : 0;
        const int vO = cur ? 12288 : 8192;
        const float* Bl = reinterpret_cast<const float*>(&SM[cur ? 16512 : 16384]);

        // key bias (broadcast reads); k = t2*32 + (r&3)+8*(r>>2)+4*hi
        f32x4 bb[2][4];
#pragma unroll
        for (int t2 = 0; t2 < 2; ++t2)
#pragma unroll
            for (int g2 = 0; g2 < 4; ++g2)
                bb[t2][g2] = *reinterpret_cast<const f32x4*>(Bl + t2 * 32 + g2 * 8 + hi * 4);

        f32x16 st[2][2];
#pragma unroll
        for (int qb = 0; qb < 2; ++qb)
#pragma unroll
            for (int t2 = 0; t2 < 2; ++t2)
#pragma unroll
                for (int g2 = 0; g2 < 4; ++g2)
#pragma unroll
                    for (int j = 0; j < 4; ++j) st[qb][t2][g2 * 4 + j] = bb[t2][g2][j];

        // S^T = K * Q^T : each K-frag read feeds both qb
        __builtin_amdgcn_s_setprio(1);
#pragma unroll
        for (int kc = 0; kc < 4; ++kc)
#pragma unroll
            for (int t2 = 0; t2 < 2; ++t2) {
                bf16x8 kf = *reinterpret_cast<const bf16x8*>(
                    &SM[kO + (t2 * 32 + l31) * 64 + ((((kc << 1) | hi) ^ l7) << 3)]);
                st[0][t2] = mfma32(kf, qf[0][kc], st[0][t2]);
                st[1][t2] = mfma32(kf, qf[1][kc], st[1][t2]);
            }
        __builtin_amdgcn_s_setprio(0);

        // softmax numerator: p = exp2(s), running per-lane denominator (no max needed)
#pragma unroll
        for (int qb = 0; qb < 2; ++qb) {
            float r0 = 0.f, r1 = 0.f;
#pragma unroll
            for (int i = 0; i < 16; ++i) {
                float p0 = exp2a(st[qb][0][i]); st[qb][0][i] = p0; r0 += p0;
                float p1 = exp2a(st[qb][1][i]); st[qb][1][i] = p1; r1 += p1;
            }
            lrun[qb] += r0 + r1;
        }

        // P^T -> bf16 B-frags via cvt_pk + permlane32_swap, then O^T += V^T * P^T
#pragma unroll
        for (int t2 = 0; t2 < 2; ++t2) {
            bf16x8 fA[2], fB[2];
#pragma unroll
            for (int qb = 0; qb < 2; ++qb) {
                unsigned w0 = cvtpk(st[qb][t2][0], st[qb][t2][1]);     // keys (0,1)+4hi
                unsigned w1 = cvtpk(st[qb][t2][2], st[qb][t2][3]);     // keys (2,3)+4hi
                unsigned w2 = cvtpk(st[qb][t2][4], st[qb][t2][5]);     // keys (8,9)+4hi
                unsigned w3 = cvtpk(st[qb][t2][6], st[qb][t2][7]);     // keys (10,11)+4hi
                unsigned w4 = cvtpk(st[qb][t2][8], st[qb][t2][9]);     // keys (16,17)+4hi
                unsigned w5 = cvtpk(st[qb][t2][10], st[qb][t2][11]);   // keys (18,19)+4hi
                unsigned w6 = cvtpk(st[qb][t2][12], st[qb][t2][13]);   // keys (24,25)+4hi
                unsigned w7 = cvtpk(st[qb][t2][14], st[qb][t2][15]);   // keys (26,27)+4hi
                plswap(w0, w2); plswap(w1, w3); plswap(w4, w6); plswap(w5, w7);
                u32x4 p0, p1;
                p0[0] = w0; p0[1] = w1; p0[2] = w2; p0[3] = w3;
                p1[0] = w4; p1[1] = w5; p1[2] = w6; p1[3] = w7;
                fA[qb] = __builtin_bit_cast(bf16x8, p0);
                fB[qb] = __builtin_bit_cast(bf16x8, p1);
            }
            const int kb0 = t2 * 2, kb1 = t2 * 2 + 1;
            __builtin_amdgcn_s_setprio(1);
#pragma unroll
            for (int dj = 0; dj < 2; ++dj) {
                bf16x8 v0 = *reinterpret_cast<const bf16x8*>(
                    &SM[vO + (dj * 32 + l31) * 64 + ((((kb0 << 1) | hi) ^ l7) << 3)]);
                bf16x8 v1 = *reinterpret_cast<const bf16x8*>(
                    &SM[vO + (dj * 32 + l31) * 64 + ((((kb1 << 1) | hi) ^ l7) << 3)]);
                ot[0][dj] = mfma32(v0, fA[0], ot[0][dj]);
                ot[0][dj] = mfma32(v1, fB[0], ot[0][dj]);
                ot[1][dj] = mfma32(v0, fA[1], ot[1][dj]);
                ot[1][dj] = mfma32(v1, fB[1], ot[1][dj]);
            }
            __builtin_amdgcn_s_setprio(0);
        }
        cur ^= 1;
    }

    // combine the two half-row denominators once
    lrun[0] += __shfl_xor(lrun[0], 32);
    lrun[1] += __shfl_xor(lrun[1], 32);

    __syncthreads();
    // epilogue: O^T -> LDS [256 q][72] -> coalesced global store
#pragma unroll
    for (int qb = 0; qb < 2; ++qb) {
        float inv = 1.0f / lrun[qb];
        const int base = (w * 64 + qb * 32 + l31) * 72;
#pragma unroll
        for (int dj = 0; dj < 2; ++dj)
#pragma unroll
            for (int i = 0; i < 8; ++i) {
                unsigned pr = cvtpk(ot[qb][dj][2 * i] * inv, ot[qb][dj][2 * i + 1] * inv);
                int d0 = dj * 32 + 2 * (i & 1) + 8 * (i >> 1) + 4 * hi;
                *reinterpret_cast<unsigned*>(&SM[base + d0]) = pr;
            }
    }
    __syncthreads();
    const int b = bh >> 4, h = bh & 15;
#pragma unroll
    for (int pass = 0; pass < 8; ++pass) {
        int row = pass * 32 + (tid >> 3);
        int seg = tid & 7;
        u32x4 vdat = *reinterpret_cast<const u32x4*>(&SM[row * 72 + seg * 8]);
        int l = qt * 256 + row;
        *reinterpret_cast<u32x4*>(Ob + ((size_t)b * 2048 + l) * 1024 + h * 64 + seg * 8) = vdat;
    }
}

extern "C" void kernel_launch(void* const* d_in, const int* in_sizes, int n_in,
                              void* d_out, int out_size, void* d_ws, size_t ws_size,
                              hipStream_t stream) {
    const float* query = (const float*)d_in[0];
    const float* key   = (const float*)d_in[1];
    const float* value = (const float*)d_in[2];
    const float* Wq = (const float*)d_in[3];
    const float* bq = (const float*)d_in[4];
    const float* Wk = (const float*)d_in[5];
    const float* bk = (const float*)d_in[6];
    const float* Wv = (const float*)d_in[7];
    const float* bv = (const float*)d_in[8];
    const float* Wo = (const float*)d_in[9];
    const float* bo = (const float*)d_in[10];

    unsigned short* VbT = (unsigned short*)d_ws;     // (B*H, 64, L)
    unsigned short* wq = VbT + 8388608;              // 1024*1024 each
    unsigned short* wk = wq + 1048576;
    unsigned short* wv = wk + 1048576;
    unsigned short* wo = wv + 1048576;
    unsigned short* Qb = wo + 1048576;               // (B*H, L, 64)
    unsigned short* Kb = Qb + 8388608;
    unsigned short* Vb = Kb + 8388608;               // (B*H, L, 64)
    unsigned short* Ob = Vb + 8388608;               // (B, L, E)
    float* biask = (float*)(Ob + 8388608);           // 131072 f32

    k_cvtw<<<dim3(256, 4), 256, 0, stream>>>(Wq, Wk, Wv, Wo, wq, wk, wv, wo);

    k_gemm_qkv<<<1536, 256, 0, stream>>>(query, key, value, wq, wk, wv,
                                         bq, bk, bv, Qb, Kb, Vb, biask);

    k_vt<<<2048, 256, 0, stream>>>(Vb, VbT);

    k_attn5<<<512, 256, 0, stream>>>(Qb, Kb, VbT, biask, Ob);

    k_gemm_out<<<512, 256, 0, stream>>>(Ob, wo, bo, (float*)d_out);
}

// Round 11
// 198.029 us; speedup vs baseline: 1.1483x; 1.0799x over previous
//
#include <hip/hip_runtime.h>
#include <hip/hip_bf16.h>
#include <stdint.h>

#define DEV __device__ __forceinline__

typedef __attribute__((ext_vector_type(8))) __bf16 bf16x8;
typedef __attribute__((ext_vector_type(4))) float f32x4;
typedef __attribute__((ext_vector_type(16))) float f32x16;
typedef __attribute__((ext_vector_type(2))) unsigned int u32x2;
typedef __attribute__((ext_vector_type(4))) unsigned int u32x4;

#define LOG2E 1.44269504088896f

DEV unsigned short f2bf(float f) {
    union { float f; unsigned int u; } v; v.f = f;
    unsigned int u = v.u;
    return (unsigned short)((u + 0x7FFFu + ((u >> 16) & 1u)) >> 16);
}
DEV float bf2f(unsigned short s) {
    union { unsigned int u; float f; } v; v.u = ((unsigned int)s) << 16;
    return v.f;
}

DEV f32x4 mfma16(bf16x8 a, bf16x8 b, f32x4 c) {
    return __builtin_amdgcn_mfma_f32_16x16x32_bf16(a, b, c, 0, 0, 0);
}
DEV f32x16 mfma32(bf16x8 a, bf16x8 b, f32x16 c) {
    return __builtin_amdgcn_mfma_f32_32x32x16_bf16(a, b, c, 0, 0, 0);
}
DEV float exp2a(float x) { float r; asm("v_exp_f32 %0, %1" : "=v"(r) : "v"(x)); return r; }
DEV unsigned cvtpk(float lo, float hi) {
    unsigned r; asm("v_cvt_pk_bf16_f32 %0, %1, %2" : "=v"(r) : "v"(lo), "v"(hi)); return r;
}
// After call: x' = [x_lo | y_lo], y' = [x_hi | y_hi]   (lane blocks of 32) — verified R5
DEV void plswap(unsigned& x, unsigned& y) {
    asm volatile("v_permlane32_swap_b32 %0, %1" : "+v"(x), "+v"(y));
}

#define GLOAD_LDS16(g, l)                                                          \
    __builtin_amdgcn_global_load_lds((__attribute__((address_space(1))) void*)(g), \
                                     (__attribute__((address_space(3))) void*)(l), \
                                     16, 0, 0)

#define VMCNT(N) asm volatile("s_waitcnt vmcnt(" #N ")" ::: "memory")
#define LGKM0    asm volatile("s_waitcnt lgkmcnt(0)" ::: "memory")
#define RBAR()   do { __builtin_amdgcn_s_barrier(); __builtin_amdgcn_sched_barrier(0); } while (0)

// ---------------- weight f32 -> bf16 converts (4 slices in one launch) ----------------
__global__ void k_cvtw(const float* __restrict__ i0, const float* __restrict__ i1,
                       const float* __restrict__ i2, const float* __restrict__ i3,
                       unsigned short* __restrict__ o0, unsigned short* __restrict__ o1,
                       unsigned short* __restrict__ o2, unsigned short* __restrict__ o3) {
    int z = blockIdx.y;
    const float* in = z == 0 ? i0 : (z == 1 ? i1 : (z == 2 ? i2 : i3));
    unsigned short* out = z == 0 ? o0 : (z == 1 ? o1 : (z == 2 ? o2 : o3));
    float scale = z == 0 ? LOG2E : 1.0f;   // fold log2e into Wq
    int stride = gridDim.x * blockDim.x;
    for (int i = blockIdx.x * blockDim.x + threadIdx.x; i * 4 < 1048576; i += stride) {
        float4 f = reinterpret_cast<const float4*>(in)[i];
        ushort4 o;
        o.x = f2bf(f.x * scale); o.y = f2bf(f.y * scale);
        o.z = f2bf(f.z * scale); o.w = f2bf(f.w * scale);
        reinterpret_cast<ushort4*>(out)[i] = o;
    }
}

// ---------------- fused QKV GEMM: counted-vmcnt pipeline + f32-A convert-in-staging ----
// Raw s_barrier + counted vmcnt keep prefetches alive ACROSS barriers.
// LDS: As 16K single + Bs 2x16K double buffer.
// z=0: Qb (bias*log2e); z=1: Kb + biask; z=2: writes VbT DIRECTLY via LDS-staged transpose.
// R10 bug fixed: VbT epilogue l-offset is (bm&15)*128, NOT bm*128 (bm>=16 overflowed the
// (bh,d) row and scribbled past VbT into the wq buffer -> corrupted weights -> inf/NaN).
__global__ __launch_bounds__(256) void k_gemm_qkv(
    const float* __restrict__ aq, const float* __restrict__ ak, const float* __restrict__ av,
    const unsigned short* __restrict__ wq, const unsigned short* __restrict__ wk,
    const unsigned short* __restrict__ wv,
    const float* __restrict__ bq, const float* __restrict__ bk, const float* __restrict__ bv,
    unsigned short* __restrict__ Qb, unsigned short* __restrict__ Kb,
    unsigned short* __restrict__ VbT, float* __restrict__ biask) {
    __shared__ __align__(16) unsigned short SMEM[24576];   // 48 KB
    unsigned short* As = SMEM;          // [8192)
    unsigned short* Bs = SMEM + 8192;   // two 8192 buffers

    const int flat = blockIdx.x;
    const int xcd = flat & 7;
    const int bn = (flat >> 3) & 7;
    const int row = xcd * 24 + (flat >> 6);
    const int z = row >> 6;
    const int bm = row & 63;

    const float* A = z == 0 ? aq : (z == 1 ? ak : av);
    const unsigned short* Bw = z == 0 ? wq : (z == 1 ? wk : wv);
    const float* bias = z == 0 ? bq : (z == 1 ? bk : bv);
    const float bscale = z == 0 ? LOG2E : 1.0f;
    const int K = 1024;

    const int tid = threadIdx.x;
    const int lane = tid & 63, w = tid >> 6;
    const int g = lane >> 4, cc = lane & 15;
    const int wm = w >> 1, wn = w & 1;

    f32x4 acc[4][4] = {};
    const int srow = lane >> 3;
    const int scol = (lane & 7) * 8;

    float4 ar[4][2];
    auto loadA = [&](int kt) {
#pragma unroll
        for (int p = 0; p < 4; ++p) {
            int c = w * 4 + p;
            int rr = c * 8 + srow;
            const float* gA = A + (size_t)(bm * 128 + rr) * K + kt + scol;
            ar[p][0] = *reinterpret_cast<const float4*>(gA);
            ar[p][1] = *reinterpret_cast<const float4*>(gA + 4);
        }
    };
    auto writeA = [&]() {
#pragma unroll
        for (int p = 0; p < 4; ++p) {
            int c = w * 4 + p;
            u32x4 pk;
            pk[0] = cvtpk(ar[p][0].x, ar[p][0].y);
            pk[1] = cvtpk(ar[p][0].z, ar[p][0].w);
            pk[2] = cvtpk(ar[p][1].x, ar[p][1].y);
            pk[3] = cvtpk(ar[p][1].z, ar[p][1].w);
            *reinterpret_cast<u32x4*>(&As[c * 512 + srow * 64 + scol]) = pk;
        }
    };
    auto issueB = [&](int kt, int buf) {
#pragma unroll
        for (int p = 0; p < 4; ++p) {
            int c = w * 4 + p;
            int rr = c * 8 + srow;
            const unsigned short* gB = Bw + (size_t)(bn * 128 + rr) * K + kt + scol;
            GLOAD_LDS16(gB, &Bs[buf * 8192 + c * 512]);
        }
    };
    auto compute = [&](int buf) {
        const unsigned short* Bc = &Bs[buf * 8192];
#pragma unroll
        for (int kc = 0; kc < 2; ++kc) {
            bf16x8 af[4], bf[4];
#pragma unroll
            for (int i = 0; i < 4; ++i) {
                af[i] = *reinterpret_cast<const bf16x8*>(&As[(wm * 64 + i * 16 + cc) * 64 + kc * 32 + g * 8]);
                bf[i] = *reinterpret_cast<const bf16x8*>(&Bc[(wn * 64 + i * 16 + cc) * 64 + kc * 32 + g * 8]);
            }
#pragma unroll
            for (int mi = 0; mi < 4; ++mi)
#pragma unroll
                for (int nj = 0; nj < 4; ++nj)
                    acc[mi][nj] = mfma16(af[mi], bf[nj], acc[mi][nj]);
        }
    };

    // prologue + iter 0
    loadA(0);
    issueB(0, 0);                    // out: A0(8) B0(4)
    issueB(64, 1);                   // out: A0 B0 B64 = 16
    VMCNT(8);                        // drain A0 (leaves B0,B64)
    writeA();
    loadA(64);                       // out: B0 B64 A64 = 16
    VMCNT(12);                       // drain B0 (B64+A64 stay in flight)
    LGKM0; RBAR();
    compute(0);
    RBAR();
    // steady: kt = 64..896
    for (int kt = 64; kt < 960; kt += 64) {
        int c = (kt >> 6) & 1;
        issueB(kt + 64, c ^ 1);      // out: B(kt) A(kt) B(kt+64) = 16
        VMCNT(4);                    // drain B(kt)+A(kt); keep B(kt+64)
        writeA();
        loadA(kt + 64);              // out: B(kt+64) A(kt+64) = 12, both span compute
        LGKM0; RBAR();
        compute(c);
        RBAR();
    }
    // final kt=960 (c=1)
    VMCNT(0);
    writeA();
    LGKM0; RBAR();
    compute(1);

    if (z == 2) {
        // LDS-staged transpose epilogue -> VbT[(b,h,d), l] coalesced (k_vt fused away)
        __syncthreads();
        unsigned short* T = SMEM;    // 128 x 136 (stride 272B: 16B-aligned rows)
#pragma unroll
        for (int mi = 0; mi < 4; ++mi) {
#pragma unroll
            for (int nj = 0; nj < 4; ++nj) {
                int nl = wn * 64 + nj * 16 + cc;
                float bvv = bias[bn * 128 + nl];
                int m0 = wm * 64 + mi * 16 + g * 4;
                u32x2 pr;
                pr[0] = cvtpk(acc[mi][nj][0] + bvv, acc[mi][nj][1] + bvv);
                pr[1] = cvtpk(acc[mi][nj][2] + bvv, acc[mi][nj][3] + bvv);
                *reinterpret_cast<u32x2*>(&T[nl * 136 + m0]) = pr;
            }
        }
        __syncthreads();
        const int b = bm >> 4;
        const int l0 = (bm & 15) * 128;   // FIX: l = m & 2047, not bm*128
        const int h0 = bn * 2;
#pragma unroll
        for (int p = 0; p < 8; ++p) {
            int n = p * 16 + (tid >> 4);
            int chunk = tid & 15;
            u32x4 v = *reinterpret_cast<const u32x4*>(&T[n * 136 + chunk * 8]);
            int h = h0 + (n >> 6), d = n & 63;
            *reinterpret_cast<u32x4*>(
                &VbT[(((size_t)b * 16 + h) * 64 + d) * 2048 + l0 + chunk * 8]) = v;
        }
        return;
    }

    unsigned short* out = z == 0 ? Qb : Kb;
    float sq[4][4];
#pragma unroll
    for (int mi = 0; mi < 4; ++mi)
#pragma unroll
        for (int r = 0; r < 4; ++r) sq[mi][r] = 0.f;

#pragma unroll
    for (int mi = 0; mi < 4; ++mi) {
#pragma unroll
        for (int nj = 0; nj < 4; ++nj) {
            int n = bn * 128 + wn * 64 + nj * 16 + cc;
            float bvv = bias[n] * bscale;
            int h = n >> 6, d = n & 63;
#pragma unroll
            for (int r = 0; r < 4; ++r) {
                int m = bm * 128 + wm * 64 + mi * 16 + g * 4 + r;
                unsigned short us = f2bf(acc[mi][nj][r] + bvv);
                int b = m >> 11, l = m & 2047;
                out[(((size_t)b * 16 + h) * 2048 + l) * 64 + d] = us;
                if (z == 1) { float vr = bf2f(us); sq[mi][r] += vr * vr; }
            }
        }
    }
    if (z == 1) {
        const int h = bn * 2 + wn;
#pragma unroll
        for (int mi = 0; mi < 4; ++mi)
#pragma unroll
            for (int r = 0; r < 4; ++r) {
                float s = sq[mi][r];
                s += __shfl_xor(s, 1); s += __shfl_xor(s, 2);
                s += __shfl_xor(s, 4); s += __shfl_xor(s, 8);
                if (cc == 0) {
                    int m = bm * 128 + wm * 64 + mi * 16 + g * 4 + r;
                    biask[(((size_t)(m >> 11)) * 16 + h) * 2048 + (m & 2047)] =
                        -0.5f * LOG2E * s;
                }
            }
    }
}

// ---------------- final GEMM: d_out = Ob * Wo^T + bo (f32 out), XCD-remapped ----------------
__global__ __launch_bounds__(256) void k_gemm_out(const unsigned short* __restrict__ A,
                                                  const unsigned short* __restrict__ Bw,
                                                  const float* __restrict__ bias,
                                                  float* __restrict__ out) {
    __shared__ __align__(16) unsigned short As[128 * 64];
    __shared__ __align__(16) unsigned short Bs[128 * 64];
    const int K = 1024, N = 1024;
    const int flat = blockIdx.x;
    const int xcd = flat & 7;
    const int bn = (flat >> 3) & 7;
    const int bm = xcd * 8 + (flat >> 6);

    const int tid = threadIdx.x;
    const int lane = tid & 63, w = tid >> 6;
    const int g = lane >> 4, cc = lane & 15;
    const int wm = w >> 1, wn = w & 1;

    f32x4 acc[4][4] = {};
    const int srow = lane >> 3;
    const int scol = (lane & 7) * 8;

    for (int kt = 0; kt < K; kt += 64) {
#pragma unroll
        for (int p = 0; p < 4; ++p) {
            int c = w * 4 + p;
            int rr = c * 8 + srow;
            const unsigned short* gA = A + (size_t)(bm * 128 + rr) * K + kt + scol;
            GLOAD_LDS16(gA, &As[c * 512]);
            const unsigned short* gB = Bw + (size_t)(bn * 128 + rr) * K + kt + scol;
            GLOAD_LDS16(gB, &Bs[c * 512]);
        }
        __syncthreads();
#pragma unroll
        for (int kc = 0; kc < 2; ++kc) {
            bf16x8 af[4], bf[4];
#pragma unroll
            for (int i = 0; i < 4; ++i) {
                af[i] = *reinterpret_cast<const bf16x8*>(&As[(wm * 64 + i * 16 + cc) * 64 + kc * 32 + g * 8]);
                bf[i] = *reinterpret_cast<const bf16x8*>(&Bs[(wn * 64 + i * 16 + cc) * 64 + kc * 32 + g * 8]);
            }
#pragma unroll
            for (int mi = 0; mi < 4; ++mi)
#pragma unroll
                for (int nj = 0; nj < 4; ++nj)
                    acc[mi][nj] = mfma16(af[mi], bf[nj], acc[mi][nj]);
        }
        __syncthreads();
    }

#pragma unroll
    for (int mi = 0; mi < 4; ++mi) {
#pragma unroll
        for (int nj = 0; nj < 4; ++nj) {
            int n = bn * 128 + wn * 64 + nj * 16 + cc;
            float bvv = bias[n];
#pragma unroll
            for (int r = 0; r < 4; ++r) {
                int m = bm * 128 + wm * 64 + mi * 16 + g * 4 + r;
                out[(size_t)m * N + n] = acc[mi][nj][r] + bvv;
            }
        }
    }
}

// ---------------- flash attention: RBF scores bounded => NO online max ----------------
// p = exp2((qk - 0.5||k||^2) log2e); the -0.5||q||^2 row-constant cancels in softmax.
// Q (BH,L,64) bf16 pre-scaled by log2e; K (BH,L,64); VT (BH,64,L); biask = -0.5*log2e*||k||^2.
__global__ __launch_bounds__(256, 2) void k_attn5(const unsigned short* __restrict__ Q,
                                                  const unsigned short* __restrict__ K,
                                                  const unsigned short* __restrict__ VT,
                                                  const float* __restrict__ biask,
                                                  unsigned short* __restrict__ Ob) {
    // ushort offsets: K0=0, K1=4096, V0=8192, V1=12288, B0=16384, B1=16512.
    // Epilogue reuses [0, 18432) as 256x72 staging.
    __shared__ __align__(16) unsigned short SM[18432];
    const int tid = threadIdx.x;
    const int lane = tid & 63, w = tid >> 6;
    const int l31 = lane & 31, hi = lane >> 5, l7 = lane & 7;
    const int flat = blockIdx.x;
    const int bh = (flat & 7) * 8 + ((flat >> 3) & 7);   // XCD-locality remap (bijective)
    const int qt = flat >> 6;                            // 0..7 (256 queries per block)
    const size_t kvbase = (size_t)bh * 2048 * 64;
    const int q0 = qt * 256 + w * 64;

    // Q fragments (B-operand), two 32-query sub-blocks per wave
    bf16x8 qf[2][4];
#pragma unroll
    for (int qb = 0; qb < 2; ++qb)
#pragma unroll
        for (int kc = 0; kc < 4; ++kc)
            qf[qb][kc] = *reinterpret_cast<const bf16x8*>(
                Q + kvbase + (size_t)(q0 + qb * 32 + l31) * 64 + kc * 16 + hi * 8);

    f32x16 ot[2][2] = {};
    float lrun[2] = {0.f, 0.f};
    const int srow = lane >> 3;

    auto stage = [&](int buf, int t) {
        const int kO = buf ? 4096 : 0;
        const int vO = buf ? 12288 : 8192;
#pragma unroll
        for (int i = 0; i < 2; ++i) {
            int r = w * 16 + i * 8 + srow;
            int cb = l7 ^ (r & 7);   // pre-swizzled source -> linear LDS == swizzled layout
            const unsigned short* gk = K + kvbase + (size_t)(t * 64 + r) * 64 + cb * 8;
            GLOAD_LDS16(gk, &SM[kO + (w * 16 + i * 8) * 64]);
            const unsigned short* gv = VT + kvbase + (size_t)r * 2048 + t * 64 + cb * 8;
            GLOAD_LDS16(gv, &SM[vO + (w * 16 + i * 8) * 64]);
        }
        if (w == 0 && lane < 16) {
            const float* gb = biask + bh * 2048 + t * 64 + lane * 4;
            GLOAD_LDS16(gb, &SM[buf ? 16512 : 16384]);
        }
    };

    stage(0, 0);
    int cur = 0;
    for (int t = 0; t < 32; ++t) {
        __syncthreads();
        if (t + 1 < 32) stage(cur ^ 1, t + 1);
        const int kO = cur ? 4096 : 0;
        const int vO = cur ? 12288 : 8192;
        const float* Bl = reinterpret_cast<const float*>(&SM[cur ? 16512 : 16384]);

        // key bias (broadcast reads); k = t2*32 + (r&3)+8*(r>>2)+4*hi
        f32x4 bb[2][4];
#pragma unroll
        for (int t2 = 0; t2 < 2; ++t2)
#pragma unroll
            for (int g2 = 0; g2 < 4; ++g2)
                bb[t2][g2] = *reinterpret_cast<const f32x4*>(Bl + t2 * 32 + g2 * 8 + hi * 4);

        f32x16 st[2][2];
#pragma unroll
        for (int qb = 0; qb < 2; ++qb)
#pragma unroll
            for (int t2 = 0; t2 < 2; ++t2)
#pragma unroll
                for (int g2 = 0; g2 < 4; ++g2)
#pragma unroll
                    for (int j = 0; j < 4; ++j) st[qb][t2][g2 * 4 + j] = bb[t2][g2][j];

        // S^T = K * Q^T : each K-frag read feeds both qb
        __builtin_amdgcn_s_setprio(1);
#pragma unroll
        for (int kc = 0; kc < 4; ++kc)
#pragma unroll
            for (int t2 = 0; t2 < 2; ++t2) {
                bf16x8 kf = *reinterpret_cast<const bf16x8*>(
                    &SM[kO + (t2 * 32 + l31) * 64 + ((((kc << 1) | hi) ^ l7) << 3)]);
                st[0][t2] = mfma32(kf, qf[0][kc], st[0][t2]);
                st[1][t2] = mfma32(kf, qf[1][kc], st[1][t2]);
            }
        __builtin_amdgcn_s_setprio(0);

        // softmax numerator: p = exp2(s), running per-lane denominator (no max needed)
#pragma unroll
        for (int qb = 0; qb < 2; ++qb) {
            float r0 = 0.f, r1 = 0.f;
#pragma unroll
            for (int i = 0; i < 16; ++i) {
                float p0 = exp2a(st[qb][0][i]); st[qb][0][i] = p0; r0 += p0;
                float p1 = exp2a(st[qb][1][i]); st[qb][1][i] = p1; r1 += p1;
            }
            lrun[qb] += r0 + r1;
        }

        // P^T -> bf16 B-frags via cvt_pk + permlane32_swap, then O^T += V^T * P^T
#pragma unroll
        for (int t2 = 0; t2 < 2; ++t2) {
            bf16x8 fA[2], fB[2];
#pragma unroll
            for (int qb = 0; qb < 2; ++qb) {
                unsigned w0 = cvtpk(st[qb][t2][0], st[qb][t2][1]);     // keys (0,1)+4hi
                unsigned w1 = cvtpk(st[qb][t2][2], st[qb][t2][3]);     // keys (2,3)+4hi
                unsigned w2 = cvtpk(st[qb][t2][4], st[qb][t2][5]);     // keys (8,9)+4hi
                unsigned w3 = cvtpk(st[qb][t2][6], st[qb][t2][7]);     // keys (10,11)+4hi
                unsigned w4 = cvtpk(st[qb][t2][8], st[qb][t2][9]);     // keys (16,17)+4hi
                unsigned w5 = cvtpk(st[qb][t2][10], st[qb][t2][11]);   // keys (18,19)+4hi
                unsigned w6 = cvtpk(st[qb][t2][12], st[qb][t2][13]);   // keys (24,25)+4hi
                unsigned w7 = cvtpk(st[qb][t2][14], st[qb][t2][15]);   // keys (26,27)+4hi
                plswap(w0, w2); plswap(w1, w3); plswap(w4, w6); plswap(w5, w7);
                u32x4 p0, p1;
                p0[0] = w0; p0[1] = w1; p0[2] = w2; p0[3] = w3;
                p1[0] = w4; p1[1] = w5; p1[2] = w6; p1[3] = w7;
                fA[qb] = __builtin_bit_cast(bf16x8, p0);
                fB[qb] = __builtin_bit_cast(bf16x8, p1);
            }
            const int kb0 = t2 * 2, kb1 = t2 * 2 + 1;
            __builtin_amdgcn_s_setprio(1);
#pragma unroll
            for (int dj = 0; dj < 2; ++dj) {
                bf16x8 v0 = *reinterpret_cast<const bf16x8*>(
                    &SM[vO + (dj * 32 + l31) * 64 + ((((kb0 << 1) | hi) ^ l7) << 3)]);
                bf16x8 v1 = *reinterpret_cast<const bf16x8*>(
                    &SM[vO + (dj * 32 + l31) * 64 + ((((kb1 << 1) | hi) ^ l7) << 3)]);
                ot[0][dj] = mfma32(v0, fA[0], ot[0][dj]);
                ot[0][dj] = mfma32(v1, fB[0], ot[0][dj]);
                ot[1][dj] = mfma32(v0, fA[1], ot[1][dj]);
                ot[1][dj] = mfma32(v1, fB[1], ot[1][dj]);
            }
            __builtin_amdgcn_s_setprio(0);
        }
        cur ^= 1;
    }

    // combine the two half-row denominators once
    lrun[0] += __shfl_xor(lrun[0], 32);
    lrun[1] += __shfl_xor(lrun[1], 32);

    __syncthreads();
    // epilogue: O^T -> LDS [256 q][72] -> coalesced global store
#pragma unroll
    for (int qb = 0; qb < 2; ++qb) {
        float inv = 1.0f / lrun[qb];
        const int base = (w * 64 + qb * 32 + l31) * 72;
#pragma unroll
        for (int dj = 0; dj < 2; ++dj)
#pragma unroll
            for (int i = 0; i < 8; ++i) {
                unsigned pr = cvtpk(ot[qb][dj][2 * i] * inv, ot[qb][dj][2 * i + 1] * inv);
                int d0 = dj * 32 + 2 * (i & 1) + 8 * (i >> 1) + 4 * hi;
                *reinterpret_cast<unsigned*>(&SM[base + d0]) = pr;
            }
    }
    __syncthreads();
    const int b = bh >> 4, h = bh & 15;
#pragma unroll
    for (int pass = 0; pass < 8; ++pass) {
        int row = pass * 32 + (tid >> 3);
        int seg = tid & 7;
        u32x4 vdat = *reinterpret_cast<const u32x4*>(&SM[row * 72 + seg * 8]);
        int l = qt * 256 + row;
        *reinterpret_cast<u32x4*>(Ob + ((size_t)b * 2048 + l) * 1024 + h * 64 + seg * 8) = vdat;
    }
}

extern "C" void kernel_launch(void* const* d_in, const int* in_sizes, int n_in,
                              void* d_out, int out_size, void* d_ws, size_t ws_size,
                              hipStream_t stream) {
    const float* query = (const float*)d_in[0];
    const float* key   = (const float*)d_in[1];
    const float* value = (const float*)d_in[2];
    const float* Wq = (const float*)d_in[3];
    const float* bq = (const float*)d_in[4];
    const float* Wk = (const float*)d_in[5];
    const float* bk = (const float*)d_in[6];
    const float* Wv = (const float*)d_in[7];
    const float* bv = (const float*)d_in[8];
    const float* Wo = (const float*)d_in[9];
    const float* bo = (const float*)d_in[10];

    unsigned short* VbT = (unsigned short*)d_ws;     // (B*H, 64, L)
    unsigned short* wq = VbT + 8388608;              // 1024*1024 each
    unsigned short* wk = wq + 1048576;
    unsigned short* wv = wk + 1048576;
    unsigned short* wo = wv + 1048576;
    unsigned short* Qb = wo + 1048576;               // (B*H, L, 64)
    unsigned short* Kb = Qb + 8388608;
    unsigned short* Ob = Kb + 8388608;               // (B, L, E)
    float* biask = (float*)(Ob + 8388608);           // 131072 f32

    k_cvtw<<<dim3(256, 4), 256, 0, stream>>>(Wq, Wk, Wv, Wo, wq, wk, wv, wo);

    k_gemm_qkv<<<1536, 256, 0, stream>>>(query, key, value, wq, wk, wv,
                                         bq, bk, bv, Qb, Kb, VbT, biask);

    k_attn5<<<512, 256, 0, stream>>>(Qb, Kb, VbT, biask, Ob);

    k_gemm_out<<<512, 256, 0, stream>>>(Ob, wo, bo, (float*)d_out);
}

// Round 12
// 192.170 us; speedup vs baseline: 1.1834x; 1.0305x over previous
//
#include <hip/hip_runtime.h>
#include <hip/hip_bf16.h>
#include <stdint.h>

#define DEV __device__ __forceinline__

typedef __attribute__((ext_vector_type(8))) __bf16 bf16x8;
typedef __attribute__((ext_vector_type(4))) float f32x4;
typedef __attribute__((ext_vector_type(16))) float f32x16;
typedef __attribute__((ext_vector_type(2))) unsigned int u32x2;
typedef __attribute__((ext_vector_type(4))) unsigned int u32x4;

#define LOG2E 1.44269504088896f

DEV unsigned short f2bf(float f) {
    union { float f; unsigned int u; } v; v.f = f;
    unsigned int u = v.u;
    return (unsigned short)((u + 0x7FFFu + ((u >> 16) & 1u)) >> 16);
}
DEV float bf2f(unsigned short s) {
    union { unsigned int u; float f; } v; v.u = ((unsigned int)s) << 16;
    return v.f;
}

DEV f32x4 mfma16(bf16x8 a, bf16x8 b, f32x4 c) {
    return __builtin_amdgcn_mfma_f32_16x16x32_bf16(a, b, c, 0, 0, 0);
}
DEV f32x16 mfma32(bf16x8 a, bf16x8 b, f32x16 c) {
    return __builtin_amdgcn_mfma_f32_32x32x16_bf16(a, b, c, 0, 0, 0);
}
DEV float exp2a(float x) { float r; asm("v_exp_f32 %0, %1" : "=v"(r) : "v"(x)); return r; }
DEV unsigned cvtpk(float lo, float hi) {
    unsigned r; asm("v_cvt_pk_bf16_f32 %0, %1, %2" : "=v"(r) : "v"(lo), "v"(hi)); return r;
}
// After call: x' = [x_lo | y_lo], y' = [x_hi | y_hi]   (lane blocks of 32) — verified R5
DEV void plswap(unsigned& x, unsigned& y) {
    asm volatile("v_permlane32_swap_b32 %0, %1" : "+v"(x), "+v"(y));
}

#define GLOAD_LDS16(g, l)                                                          \
    __builtin_amdgcn_global_load_lds((__attribute__((address_space(1))) void*)(g), \
                                     (__attribute__((address_space(3))) void*)(l), \
                                     16, 0, 0)

#define VMCNT(N) asm volatile("s_waitcnt vmcnt(" #N ")" ::: "memory")
#define LGKM0    asm volatile("s_waitcnt lgkmcnt(0)" ::: "memory")
#define RBAR()   do { __builtin_amdgcn_s_barrier(); __builtin_amdgcn_sched_barrier(0); } while (0)

// ---------------- weight f32 -> bf16 converts (4 slices in one launch) ----------------
__global__ void k_cvtw(const float* __restrict__ i0, const float* __restrict__ i1,
                       const float* __restrict__ i2, const float* __restrict__ i3,
                       unsigned short* __restrict__ o0, unsigned short* __restrict__ o1,
                       unsigned short* __restrict__ o2, unsigned short* __restrict__ o3) {
    int z = blockIdx.y;
    const float* in = z == 0 ? i0 : (z == 1 ? i1 : (z == 2 ? i2 : i3));
    unsigned short* out = z == 0 ? o0 : (z == 1 ? o1 : (z == 2 ? o2 : o3));
    float scale = z == 0 ? LOG2E : 1.0f;   // fold log2e into Wq
    int stride = gridDim.x * blockDim.x;
    for (int i = blockIdx.x * blockDim.x + threadIdx.x; i * 4 < 1048576; i += stride) {
        float4 f = reinterpret_cast<const float4*>(in)[i];
        ushort4 o;
        o.x = f2bf(f.x * scale); o.y = f2bf(f.y * scale);
        o.z = f2bf(f.z * scale); o.w = f2bf(f.w * scale);
        reinterpret_cast<ushort4*>(out)[i] = o;
    }
}

// ---------------- fused QKV GEMM: counted-vmcnt pipeline + f32-A convert-in-staging ----
// Raw s_barrier + counted vmcnt keep prefetches alive ACROSS barriers.
// LDS: As 16K single + Bs 2x16K double buffer.
// z=0: Qb (bias*log2e); z=1: Kb + biask; z=2: writes VbT DIRECTLY via LDS-staged transpose.
__global__ __launch_bounds__(256) void k_gemm_qkv(
    const float* __restrict__ aq, const float* __restrict__ ak, const float* __restrict__ av,
    const unsigned short* __restrict__ wq, const unsigned short* __restrict__ wk,
    const unsigned short* __restrict__ wv,
    const float* __restrict__ bq, const float* __restrict__ bk, const float* __restrict__ bv,
    unsigned short* __restrict__ Qb, unsigned short* __restrict__ Kb,
    unsigned short* __restrict__ VbT, float* __restrict__ biask) {
    __shared__ __align__(16) unsigned short SMEM[24576];   // 48 KB
    unsigned short* As = SMEM;          // [8192)
    unsigned short* Bs = SMEM + 8192;   // two 8192 buffers

    const int flat = blockIdx.x;
    const int xcd = flat & 7;
    const int bn = (flat >> 3) & 7;
    const int row = xcd * 24 + (flat >> 6);
    const int z = row >> 6;
    const int bm = row & 63;

    const float* A = z == 0 ? aq : (z == 1 ? ak : av);
    const unsigned short* Bw = z == 0 ? wq : (z == 1 ? wk : wv);
    const float* bias = z == 0 ? bq : (z == 1 ? bk : bv);
    const float bscale = z == 0 ? LOG2E : 1.0f;
    const int K = 1024;

    const int tid = threadIdx.x;
    const int lane = tid & 63, w = tid >> 6;
    const int g = lane >> 4, cc = lane & 15;
    const int wm = w >> 1, wn = w & 1;

    f32x4 acc[4][4] = {};
    const int srow = lane >> 3;
    const int scol = (lane & 7) * 8;

    float4 ar[4][2];
    auto loadA = [&](int kt) {
#pragma unroll
        for (int p = 0; p < 4; ++p) {
            int c = w * 4 + p;
            int rr = c * 8 + srow;
            const float* gA = A + (size_t)(bm * 128 + rr) * K + kt + scol;
            ar[p][0] = *reinterpret_cast<const float4*>(gA);
            ar[p][1] = *reinterpret_cast<const float4*>(gA + 4);
        }
    };
    auto writeA = [&]() {
#pragma unroll
        for (int p = 0; p < 4; ++p) {
            int c = w * 4 + p;
            u32x4 pk;
            pk[0] = cvtpk(ar[p][0].x, ar[p][0].y);
            pk[1] = cvtpk(ar[p][0].z, ar[p][0].w);
            pk[2] = cvtpk(ar[p][1].x, ar[p][1].y);
            pk[3] = cvtpk(ar[p][1].z, ar[p][1].w);
            *reinterpret_cast<u32x4*>(&As[c * 512 + srow * 64 + scol]) = pk;
        }
    };
    auto issueB = [&](int kt, int buf) {
#pragma unroll
        for (int p = 0; p < 4; ++p) {
            int c = w * 4 + p;
            int rr = c * 8 + srow;
            const unsigned short* gB = Bw + (size_t)(bn * 128 + rr) * K + kt + scol;
            GLOAD_LDS16(gB, &Bs[buf * 8192 + c * 512]);
        }
    };
    auto compute = [&](int buf) {
        const unsigned short* Bc = &Bs[buf * 8192];
        __builtin_amdgcn_s_setprio(1);
#pragma unroll
        for (int kc = 0; kc < 2; ++kc) {
            bf16x8 af[4], bf[4];
#pragma unroll
            for (int i = 0; i < 4; ++i) {
                af[i] = *reinterpret_cast<const bf16x8*>(&As[(wm * 64 + i * 16 + cc) * 64 + kc * 32 + g * 8]);
                bf[i] = *reinterpret_cast<const bf16x8*>(&Bc[(wn * 64 + i * 16 + cc) * 64 + kc * 32 + g * 8]);
            }
#pragma unroll
            for (int mi = 0; mi < 4; ++mi)
#pragma unroll
                for (int nj = 0; nj < 4; ++nj)
                    acc[mi][nj] = mfma16(af[mi], bf[nj], acc[mi][nj]);
        }
        __builtin_amdgcn_s_setprio(0);
    };

    // prologue + iter 0
    loadA(0);
    issueB(0, 0);                    // out: A0(8) B0(4)
    issueB(64, 1);                   // out: A0 B0 B64 = 16
    VMCNT(8);                        // drain A0 (leaves B0,B64)
    writeA();
    loadA(64);                       // out: B0 B64 A64 = 16
    VMCNT(12);                       // drain B0 (B64+A64 stay in flight)
    LGKM0; RBAR();
    compute(0);
    RBAR();
    // steady: kt = 64..896
    for (int kt = 64; kt < 960; kt += 64) {
        int c = (kt >> 6) & 1;
        issueB(kt + 64, c ^ 1);      // out: B(kt) A(kt) B(kt+64) = 16
        VMCNT(4);                    // drain B(kt)+A(kt); keep B(kt+64)
        writeA();
        loadA(kt + 64);              // out: B(kt+64) A(kt+64) = 12, both span compute
        LGKM0; RBAR();
        compute(c);
        RBAR();
    }
    // final kt=960 (c=1)
    VMCNT(0);
    writeA();
    LGKM0; RBAR();
    compute(1);

    if (z == 2) {
        // LDS-staged transpose epilogue -> VbT[(b,h,d), l] coalesced (k_vt fused away)
        __syncthreads();
        unsigned short* T = SMEM;    // 128 x 136 (stride 272B: 16B-aligned rows)
#pragma unroll
        for (int mi = 0; mi < 4; ++mi) {
#pragma unroll
            for (int nj = 0; nj < 4; ++nj) {
                int nl = wn * 64 + nj * 16 + cc;
                float bvv = bias[bn * 128 + nl];
                int m0 = wm * 64 + mi * 16 + g * 4;
                u32x2 pr;
                pr[0] = cvtpk(acc[mi][nj][0] + bvv, acc[mi][nj][1] + bvv);
                pr[1] = cvtpk(acc[mi][nj][2] + bvv, acc[mi][nj][3] + bvv);
                *reinterpret_cast<u32x2*>(&T[nl * 136 + m0]) = pr;
            }
        }
        __syncthreads();
        const int b = bm >> 4;
        const int l0 = (bm & 15) * 128;   // l = m & 2047 (R10 bug fix kept)
        const int h0 = bn * 2;
#pragma unroll
        for (int p = 0; p < 8; ++p) {
            int n = p * 16 + (tid >> 4);
            int chunk = tid & 15;
            u32x4 v = *reinterpret_cast<const u32x4*>(&T[n * 136 + chunk * 8]);
            int h = h0 + (n >> 6), d = n & 63;
            *reinterpret_cast<u32x4*>(
                &VbT[(((size_t)b * 16 + h) * 64 + d) * 2048 + l0 + chunk * 8]) = v;
        }
        return;
    }

    unsigned short* out = z == 0 ? Qb : Kb;
    float sq[4][4];
#pragma unroll
    for (int mi = 0; mi < 4; ++mi)
#pragma unroll
        for (int r = 0; r < 4; ++r) sq[mi][r] = 0.f;

#pragma unroll
    for (int mi = 0; mi < 4; ++mi) {
#pragma unroll
        for (int nj = 0; nj < 4; ++nj) {
            int n = bn * 128 + wn * 64 + nj * 16 + cc;
            float bvv = bias[n] * bscale;
            int h = n >> 6, d = n & 63;
#pragma unroll
            for (int r = 0; r < 4; ++r) {
                int m = bm * 128 + wm * 64 + mi * 16 + g * 4 + r;
                unsigned short us = f2bf(acc[mi][nj][r] + bvv);
                int b = m >> 11, l = m & 2047;
                out[(((size_t)b * 16 + h) * 2048 + l) * 64 + d] = us;
                if (z == 1) { float vr = bf2f(us); sq[mi][r] += vr * vr; }
            }
        }
    }
    if (z == 1) {
        const int h = bn * 2 + wn;
#pragma unroll
        for (int mi = 0; mi < 4; ++mi)
#pragma unroll
            for (int r = 0; r < 4; ++r) {
                float s = sq[mi][r];
                s += __shfl_xor(s, 1); s += __shfl_xor(s, 2);
                s += __shfl_xor(s, 4); s += __shfl_xor(s, 8);
                if (cc == 0) {
                    int m = bm * 128 + wm * 64 + mi * 16 + g * 4 + r;
                    biask[(((size_t)(m >> 11)) * 16 + h) * 2048 + (m & 2047)] =
                        -0.5f * LOG2E * s;
                }
            }
    }
}

// ---------------- final GEMM: counted-vmcnt pipelined, XCD-remapped, f32 out ------------
// Full A+B double buffer (64KB LDS). Per iter: VMCNT(8) [drain stage(kt), keep
// stage(kt+64) in flight]; RBAR; compute(c); RBAR; stage(kt+128 -> buf c).
__global__ __launch_bounds__(256) void k_gemm_out(const unsigned short* __restrict__ A,
                                                  const unsigned short* __restrict__ Bw,
                                                  const float* __restrict__ bias,
                                                  float* __restrict__ out) {
    __shared__ __align__(16) unsigned short SMEM[32768];   // 64 KB: 2 bufs x (As+Bs)
    const int K = 1024, N = 1024;
    const int flat = blockIdx.x;
    const int xcd = flat & 7;
    const int bn = (flat >> 3) & 7;
    const int bm = xcd * 8 + (flat >> 6);

    const int tid = threadIdx.x;
    const int lane = tid & 63, w = tid >> 6;
    const int g = lane >> 4, cc = lane & 15;
    const int wm = w >> 1, wn = w & 1;

    f32x4 acc[4][4] = {};
    const int srow = lane >> 3;
    const int scol = (lane & 7) * 8;

    auto stage = [&](int kt, int buf) {
        unsigned short* SB = &SMEM[buf * 16384];
#pragma unroll
        for (int p = 0; p < 4; ++p) {
            int c = w * 4 + p;
            int rr = c * 8 + srow;
            const unsigned short* gA = A + (size_t)(bm * 128 + rr) * K + kt + scol;
            GLOAD_LDS16(gA, &SB[c * 512]);
            const unsigned short* gB = Bw + (size_t)(bn * 128 + rr) * K + kt + scol;
            GLOAD_LDS16(gB, &SB[8192 + c * 512]);
        }
    };
    auto compute = [&](int buf) {
        const unsigned short* SB = &SMEM[buf * 16384];
        __builtin_amdgcn_s_setprio(1);
#pragma unroll
        for (int kc = 0; kc < 2; ++kc) {
            bf16x8 af[4], bf[4];
#pragma unroll
            for (int i = 0; i < 4; ++i) {
                af[i] = *reinterpret_cast<const bf16x8*>(&SB[(wm * 64 + i * 16 + cc) * 64 + kc * 32 + g * 8]);
                bf[i] = *reinterpret_cast<const bf16x8*>(&SB[8192 + (wn * 64 + i * 16 + cc) * 64 + kc * 32 + g * 8]);
            }
#pragma unroll
            for (int mi = 0; mi < 4; ++mi)
#pragma unroll
                for (int nj = 0; nj < 4; ++nj)
                    acc[mi][nj] = mfma16(af[mi], bf[nj], acc[mi][nj]);
        }
        __builtin_amdgcn_s_setprio(0);
    };

    stage(0, 0);
    stage(64, 1);
    // kt = 0..896: VMCNT(8) keeps next stage's 8 loads in flight
    for (int kt = 0; kt < 960; kt += 64) {
        int c = (kt >> 6) & 1;
        VMCNT(8);                    // stage(kt) landed; stage(kt+64) stays in flight
        RBAR();
        compute(c);
        RBAR();
        if (kt + 128 < K) stage(kt + 128, c);
    }
    // final kt=960 (c=1): only stage(960) outstanding
    VMCNT(0);
    RBAR();
    compute(1);

#pragma unroll
    for (int mi = 0; mi < 4; ++mi) {
#pragma unroll
        for (int nj = 0; nj < 4; ++nj) {
            int n = bn * 128 + wn * 64 + nj * 16 + cc;
            float bvv = bias[n];
#pragma unroll
            for (int r = 0; r < 4; ++r) {
                int m = bm * 128 + wm * 64 + mi * 16 + g * 4 + r;
                out[(size_t)m * N + n] = acc[mi][nj][r] + bvv;
            }
        }
    }
}

// ---------------- flash attention: RBF scores bounded => NO online max ----------------
// p = exp2((qk - 0.5||k||^2) log2e); the -0.5||q||^2 row-constant cancels in softmax.
// Q (BH,L,64) bf16 pre-scaled by log2e; K (BH,L,64); VT (BH,64,L); biask = -0.5*log2e*||k||^2.
__global__ __launch_bounds__(256, 2) void k_attn5(const unsigned short* __restrict__ Q,
                                                  const unsigned short* __restrict__ K,
                                                  const unsigned short* __restrict__ VT,
                                                  const float* __restrict__ biask,
                                                  unsigned short* __restrict__ Ob) {
    // ushort offsets: K0=0, K1=4096, V0=8192, V1=12288, B0=16384, B1=16512.
    // Epilogue reuses [0, 18432) as 256x72 staging.
    __shared__ __align__(16) unsigned short SM[18432];
    const int tid = threadIdx.x;
    const int lane = tid & 63, w = tid >> 6;
    const int l31 = lane & 31, hi = lane >> 5, l7 = lane & 7;
    const int flat = blockIdx.x;
    const int bh = (flat & 7) * 8 + ((flat >> 3) & 7);   // XCD-locality remap (bijective)
    const int qt = flat >> 6;                            // 0..7 (256 queries per block)
    const size_t kvbase = (size_t)bh * 2048 * 64;
    const int q0 = qt * 256 + w * 64;

    // Q fragments (B-operand), two 32-query sub-blocks per wave
    bf16x8 qf[2][4];
#pragma unroll
    for (int qb = 0; qb < 2; ++qb)
#pragma unroll
        for (int kc = 0; kc < 4; ++kc)
            qf[qb][kc] = *reinterpret_cast<const bf16x8*>(
                Q + kvbase + (size_t)(q0 + qb * 32 + l31) * 64 + kc * 16 + hi * 8);

    f32x16 ot[2][2] = {};
    float lrun[2] = {0.f, 0.f};
    const int srow = lane >> 3;

    auto stage = [&](int buf, int t) {
        const int kO = buf ? 4096 : 0;
        const int vO = buf ? 12288 : 8192;
#pragma unroll
        for (int i = 0; i < 2; ++i) {
            int r = w * 16 + i * 8 + srow;
            int cb = l7 ^ (r & 7);   // pre-swizzled source -> linear LDS == swizzled layout
            const unsigned short* gk = K + kvbase + (size_t)(t * 64 + r) * 64 + cb * 8;
            GLOAD_LDS16(gk, &SM[kO + (w * 16 + i * 8) * 64]);
            const unsigned short* gv = VT + kvbase + (size_t)r * 2048 + t * 64 + cb * 8;
            GLOAD_LDS16(gv, &SM[vO + (w * 16 + i * 8) * 64]);
        }
        if (w == 0 && lane < 16) {
            const float* gb = biask + bh * 2048 + t * 64 + lane * 4;
            GLOAD_LDS16(gb, &SM[buf ? 16512 : 16384]);
        }
    };

    stage(0, 0);
    int cur = 0;
    for (int t = 0; t < 32; ++t) {
        __syncthreads();
        if (t + 1 < 32) stage(cur ^ 1, t + 1);
        const int kO = cur ? 4096 : 0;
        const int vO = cur ? 12288 : 8192;
        const float* Bl = reinterpret_cast<const float*>(&SM[cur ? 16512 : 16384]);

        // key bias (broadcast reads); k = t2*32 + (r&3)+8*(r>>2)+4*hi
        f32x4 bb[2][4];
#pragma unroll
        for (int t2 = 0; t2 < 2; ++t2)
#pragma unroll
            for (int g2 = 0; g2 < 4; ++g2)
                bb[t2][g2] = *reinterpret_cast<const f32x4*>(Bl + t2 * 32 + g2 * 8 + hi * 4);

        f32x16 st[2][2];
#pragma unroll
        for (int qb = 0; qb < 2; ++qb)
#pragma unroll
            for (int t2 = 0; t2 < 2; ++t2)
#pragma unroll
                for (int g2 = 0; g2 < 4; ++g2)
#pragma unroll
                    for (int j = 0; j < 4; ++j) st[qb][t2][g2 * 4 + j] = bb[t2][g2][j];

        // S^T = K * Q^T : each K-frag read feeds both qb
        __builtin_amdgcn_s_setprio(1);
#pragma unroll
        for (int kc = 0; kc < 4; ++kc)
#pragma unroll
            for (int t2 = 0; t2 < 2; ++t2) {
                bf16x8 kf = *reinterpret_cast<const bf16x8*>(
                    &SM[kO + (t2 * 32 + l31) * 64 + ((((kc << 1) | hi) ^ l7) << 3)]);
                st[0][t2] = mfma32(kf, qf[0][kc], st[0][t2]);
                st[1][t2] = mfma32(kf, qf[1][kc], st[1][t2]);
            }
        __builtin_amdgcn_s_setprio(0);

        // softmax numerator: p = exp2(s), running per-lane denominator (no max needed)
#pragma unroll
        for (int qb = 0; qb < 2; ++qb) {
            float r0 = 0.f, r1 = 0.f;
#pragma unroll
            for (int i = 0; i < 16; ++i) {
                float p0 = exp2a(st[qb][0][i]); st[qb][0][i] = p0; r0 += p0;
                float p1 = exp2a(st[qb][1][i]); st[qb][1][i] = p1; r1 += p1;
            }
            lrun[qb] += r0 + r1;
        }

        // P^T -> bf16 B-frags via cvt_pk + permlane32_swap, then O^T += V^T * P^T
#pragma unroll
        for (int t2 = 0; t2 < 2; ++t2) {
            bf16x8 fA[2], fB[2];
#pragma unroll
            for (int qb = 0; qb < 2; ++qb) {
                unsigned w0 = cvtpk(st[qb][t2][0], st[qb][t2][1]);     // keys (0,1)+4hi
                unsigned w1 = cvtpk(st[qb][t2][2], st[qb][t2][3]);     // keys (2,3)+4hi
                unsigned w2 = cvtpk(st[qb][t2][4], st[qb][t2][5]);     // keys (8,9)+4hi
                unsigned w3 = cvtpk(st[qb][t2][6], st[qb][t2][7]);     // keys (10,11)+4hi
                unsigned w4 = cvtpk(st[qb][t2][8], st[qb][t2][9]);     // keys (16,17)+4hi
                unsigned w5 = cvtpk(st[qb][t2][10], st[qb][t2][11]);   // keys (18,19)+4hi
                unsigned w6 = cvtpk(st[qb][t2][12], st[qb][t2][13]);   // keys (24,25)+4hi
                unsigned w7 = cvtpk(st[qb][t2][14], st[qb][t2][15]);   // keys (26,27)+4hi
                plswap(w0, w2); plswap(w1, w3); plswap(w4, w6); plswap(w5, w7);
                u32x4 p0, p1;
                p0[0] = w0; p0[1] = w1; p0[2] = w2; p0[3] = w3;
                p1[0] = w4; p1[1] = w5; p1[2] = w6; p1[3] = w7;
                fA[qb] = __builtin_bit_cast(bf16x8, p0);
                fB[qb] = __builtin_bit_cast(bf16x8, p1);
            }
            const int kb0 = t2 * 2, kb1 = t2 * 2 + 1;
            __builtin_amdgcn_s_setprio(1);
#pragma unroll
            for (int dj = 0; dj < 2; ++dj) {
                bf16x8 v0 = *reinterpret_cast<const bf16x8*>(
                    &SM[vO + (dj * 32 + l31) * 64 + ((((kb0 << 1) | hi) ^ l7) << 3)]);
                bf16x8 v1 = *reinterpret_cast<const bf16x8*>(
                    &SM[vO + (dj * 32 + l31) * 64 + ((((kb1 << 1) | hi) ^ l7) << 3)]);
                ot[0][dj] = mfma32(v0, fA[0], ot[0][dj]);
                ot[0][dj] = mfma32(v1, fB[0], ot[0][dj]);
                ot[1][dj] = mfma32(v0, fA[1], ot[1][dj]);
                ot[1][dj] = mfma32(v1, fB[1], ot[1][dj]);
            }
            __builtin_amdgcn_s_setprio(0);
        }
        cur ^= 1;
    }

    // combine the two half-row denominators once
    lrun[0] += __shfl_xor(lrun[0], 32);
    lrun[1] += __shfl_xor(lrun[1], 32);

    __syncthreads();
    // epilogue: O^T -> LDS [256 q][72] -> coalesced global store
#pragma unroll
    for (int qb = 0; qb < 2; ++qb) {
        float inv = 1.0f / lrun[qb];
        const int base = (w * 64 + qb * 32 + l31) * 72;
#pragma unroll
        for (int dj = 0; dj < 2; ++dj)
#pragma unroll
            for (int i = 0; i < 8; ++i) {
                unsigned pr = cvtpk(ot[qb][dj][2 * i] * inv, ot[qb][dj][2 * i + 1] * inv);
                int d0 = dj * 32 + 2 * (i & 1) + 8 * (i >> 1) + 4 * hi;
                *reinterpret_cast<unsigned*>(&SM[base + d0]) = pr;
            }
    }
    __syncthreads();
    const int b = bh >> 4, h = bh & 15;
#pragma unroll
    for (int pass = 0; pass < 8; ++pass) {
        int row = pass * 32 + (tid >> 3);
        int seg = tid & 7;
        u32x4 vdat = *reinterpret_cast<const u32x4*>(&SM[row * 72 + seg * 8]);
        int l = qt * 256 + row;
        *reinterpret_cast<u32x4*>(Ob + ((size_t)b * 2048 + l) * 1024 + h * 64 + seg * 8) = vdat;
    }
}

extern "C" void kernel_launch(void* const* d_in, const int* in_sizes, int n_in,
                              void* d_out, int out_size, void* d_ws, size_t ws_size,
                              hipStream_t stream) {
    const float* query = (const float*)d_in[0];
    const float* key   = (const float*)d_in[1];
    const float* value = (const float*)d_in[2];
    const float* Wq = (const float*)d_in[3];
    const float* bq = (const float*)d_in[4];
    const float* Wk = (const float*)d_in[5];
    const float* bk = (const float*)d_in[6];
    const float* Wv = (const float*)d_in[7];
    const float* bv = (const float*)d_in[8];
    const float* Wo = (const float*)d_in[9];
    const float* bo = (const float*)d_in[10];

    unsigned short* VbT = (unsigned short*)d_ws;     // (B*H, 64, L)
    unsigned short* wq = VbT + 8388608;              // 1024*1024 each
    unsigned short* wk = wq + 1048576;
    unsigned short* wv = wk + 1048576;
    unsigned short* wo = wv + 1048576;
    unsigned short* Qb = wo + 1048576;               // (B*H, L, 64)
    unsigned short* Kb = Qb + 8388608;
    unsigned short* Ob = Kb + 8388608;               // (B, L, E)
    float* biask = (float*)(Ob + 8388608);           // 131072 f32

    k_cvtw<<<dim3(256, 4), 256, 0, stream>>>(Wq, Wk, Wv, Wo, wq, wk, wv, wo);

    k_gemm_qkv<<<1536, 256, 0, stream>>>(query, key, value, wq, wk, wv,
                                         bq, bk, bv, Qb, Kb, VbT, biask);

    k_attn5<<<512, 256, 0, stream>>>(Qb, Kb, VbT, biask, Ob);

    k_gemm_out<<<512, 256, 0, stream>>>(Ob, wo, bo, (float*)d_out);
}